// Round 6
// baseline (478.682 us; speedup 1.0000x reference)
//
#include <hip/hip_runtime.h>
#include <hip/hip_bf16.h>
#include <math.h>

#define LRELU 0.01f

// ---------- vectorized LDS weight fetch ----------
template<int NW>
__device__ __forceinline__ void ldw(const float* p, float* w) {
    if constexpr (NW % 4 == 0) {
#pragma unroll
        for (int u = 0; u < NW / 4; u++) {
            float4 v = *(const float4*)(p + 4 * u);
            w[4*u] = v.x; w[4*u+1] = v.y; w[4*u+2] = v.z; w[4*u+3] = v.w;
        }
    } else {
#pragma unroll
        for (int c = 0; c < NW; c++) w[c] = p[c];
    }
}

// ======================= fused prep =======================
__device__ __forceinline__ void wfwd(const float* s, float* d, int CIN, int COUT,
                                     int KK, int i) {
    int co = i / (CIN * KK); int r = i - co * CIN * KK;
    int ci = r / KK; int t = r - ci * KK;
    d[(ci * KK + t) * COUT + co] = s[i];
}
__device__ __forceinline__ void wtr(const float* s, float* d, int CIN, int COUT,
                                    int KK, int i) {
    int ci = i / (COUT * KK); int r = i - ci * COUT * KK;
    int co = r / KK; int t = r - co * KK;
    d[(t * CIN + ci) * COUT + co] = s[i];
}
__global__ __launch_bounds__(256)
void prep_k(const float* e1, const float* e2, const float* e3, const float* e4,
            const float* e5, const float* d1, const float* d2, const float* d3,
            const float* d4, float* w, const float* cbp, float* hcbn,
            unsigned long long* keys, float* loss, int* idxm, int N) {
    int i = blockIdx.x * 256 + threadIdx.x;
    if      (i < 128)   wfwd(e1, w + 0,     1,  8, 16, i);
    else if (i < 2176)  wfwd(e2, w + 128,   8, 16, 16, i - 128);
    else if (i < 10368) wfwd(e3, w + 2176, 16, 32, 16, i - 2176);
    else if (i < 19584) wfwd(e4, w + 10368, 32, 32, 9, i - 10368);
    else if (i < 21632) wfwd(e5, w + 19584, 32, 64, 1, i - 19584);
    else if (i < 40064) wfwd(d1, w + 21632, 64, 32, 9, i - 21632);
    else if (i < 48256) wtr (d2, w + 40064, 32, 16, 16, i - 40064);
    else if (i < 50304) wtr (d3, w + 48256, 16,  8, 16, i - 48256);
    else if (i < 50432) wtr (d4, w + 50304,  8,  1, 16, i - 50304);
    else if (i < 50944) {
        int k = i - 50432;
        const float* c = cbp + k * 64;
        float s = 0.f;
#pragma unroll
        for (int d = 0; d < 64; d++) s = fmaf(c[d], c[d], s);
        hcbn[k] = 0.5f * s;
    } else if (i < 50944 + N) {
        keys[i - 50944] = 0xFFFFFFFFFFFFFFFFull;
    } else if (i == 50944 + N) {
        loss[0] = 0.f;
    } else if (i < 50945 + N + 64 * 124) {
        // idx-map padding frame = sentinel 512 (U[512] == 0)
        int j = i - (50945 + N);
        int b2 = j / 124, s = j - b2 * 124;
        int r, c;
        if (s < 32)      { r = 0;  c = s; }
        else if (s < 64) { r = 31; c = s - 32; }
        else { int u = s - 64; r = 1 + (u >> 1); c = (u & 1) * 31; }
        idxm[b2 * 1024 + r * 32 + c] = 512;
    }
}

// ======================= U table =======================
__global__ __launch_bounds__(256)
void ubuild_k(const float* __restrict__ w, const float* __restrict__ cb,
              float* __restrict__ U) {
    int g = blockIdx.x * 256 + threadIdx.x;
    if (g >= 513 * 288) return;
    if (g >= 512 * 288) { U[g] = 0.f; return; }
    int k = g / 288, rem = g - k * 288;
    const float* cr = cb + k * 64;
    float s = 0.f;
#pragma unroll 4
    for (int ci = 0; ci < 64; ci++)
        s = fmaf(w[ci * 288 + rem], cr[ci], s);
    U[g] = s;
}

// ======================= k4 s2 forward conv (+frame-zero slices) ============
template<int CIN, int COUT, int CO_BLK, int HIN, int ISTR, int HOUT, int WOUT,
         int OPLANE, int OSTR, int OPAD, int CB, int RB, int ZCONV, int ZF_CH>
__global__ __launch_bounds__(256)
void convs2_k(const float* __restrict__ in, const float* __restrict__ wt,
              const float* __restrict__ bias, float* __restrict__ out) {
    const int b = blockIdx.x, cog = blockIdx.y, tid = threadIdx.x;
    if (ZF_CH > 0 && (int)blockIdx.z >= ZCONV) {
        if (cog != 0) return;
        int i = ((int)blockIdx.z - ZCONV) * 256 + tid;
        if (i >= ZF_CH * 124) return;
        int ch = i / 124, s = i - ch * 124;
        int r, c;
        if (s < 32)      { r = 0;  c = s; }
        else if (s < 64) { r = 31; c = s - 32; }
        else { int u = s - 64; r = 1 + (u >> 1); c = (u & 1) * 31; }
        out[(size_t)(b * ZF_CH + ch) * 1024 + r * 32 + c] = 0.f;
        return;
    }
    __shared__ __align__(16) float lw[CIN * 16 * CO_BLK];
    for (int i = tid; i < CIN * 16 * CO_BLK; i += 256) {
        int row = i / CO_BLK, c = i - row * CO_BLK;
        lw[i] = wt[row * COUT + cog * CO_BLK + c];
    }
    __syncthreads();

    const int tz = blockIdx.z;
    const int cbi = tz / RB, rb = tz - cbi * RB;
    const int tx = tid & 15, ty = tid >> 4;
    const int ow0 = (cbi * 16 + tx) * 2;
    const int oh  = rb * 16 + ty;
    if (oh >= HOUT || ow0 >= WOUT) return;
    const bool p1v = (ow0 + 1) < WOUT;

    float acc[CO_BLK][2];
#pragma unroll
    for (int c = 0; c < CO_BLK; c++) {
        float bv = bias[cog * CO_BLK + c];
        acc[c][0] = bv; acc[c][1] = bv;
    }
    const float* inb = in + ((size_t)(b * CIN) * HIN + oh * 2) * ISTR + ow0 * 2;
#pragma unroll 2
    for (int ci = 0; ci < CIN; ci++) {
        const float* r = inb + (size_t)ci * HIN * ISTR;
        float4 a4[4]; float2 b2[4];
#pragma unroll
        for (int kh = 0; kh < 4; kh++) {
            a4[kh] = *(const float4*)(r + kh * ISTR);
            b2[kh] = p1v ? *(const float2*)(r + kh * ISTR + 4) : make_float2(0.f, 0.f);
        }
        const float* wr = lw + ci * 16 * CO_BLK;
#pragma unroll
        for (int kh = 0; kh < 4; kh++) {
            float x0[4] = {a4[kh].x, a4[kh].y, a4[kh].z, a4[kh].w};
            float x1[4] = {a4[kh].z, a4[kh].w, b2[kh].x, b2[kh].y};
#pragma unroll
            for (int kw = 0; kw < 4; kw++) {
                float wv[CO_BLK];
                ldw<CO_BLK>(wr + (kh * 4 + kw) * CO_BLK, wv);
#pragma unroll
                for (int c = 0; c < CO_BLK; c++) {
                    acc[c][0] = fmaf(x0[kw], wv[c], acc[c][0]);
                    acc[c][1] = fmaf(x1[kw], wv[c], acc[c][1]);
                }
            }
        }
    }
    float* ob = out + (size_t)(b * COUT + cog * CO_BLK) * OPLANE
                    + (oh + OPAD) * OSTR + ow0 + OPAD;
#pragma unroll
    for (int c = 0; c < CO_BLK; c++) {
        float v0 = acc[c][0]; v0 = (v0 >= 0.f) ? v0 : LRELU * v0;
        ob[(size_t)c * OPLANE] = v0;
        if (p1v) {
            float v1 = acc[c][1]; v1 = (v1 >= 0.f) ? v1 : LRELU * v1;
            ob[(size_t)c * OPLANE + 1] = v1;
        }
    }
}

// ======================= k3 s1 p1 conv =======================
template<int CIN, int COUT, int CO_BLK, int OPLANE, int OSTR, int OPADH, int OPADV,
         bool ZSIDE>
__global__ __launch_bounds__(256)
void conv3_k(const float* __restrict__ in, const float* __restrict__ wt,
             const float* __restrict__ bias, float* __restrict__ out) {
    const int b = blockIdx.x, cog = blockIdx.y, tid = threadIdx.x;
    __shared__ __align__(16) float lw[CIN * 9 * CO_BLK];
    for (int i = tid; i < CIN * 9 * CO_BLK; i += 256) {
        int row = i / CO_BLK, c = i - row * CO_BLK;
        lw[i] = wt[row * COUT + cog * CO_BLK + c];
    }
    __syncthreads();

    const int rb = blockIdx.z;
    const int tx = tid & 15, ty = tid >> 4;
    const int r = rb * 16 + ty;
    if (r >= 30) return;
    const int ow0 = tx * 2;
    if (tx == 15) {
        if (ZSIDE) {
#pragma unroll
            for (int c = 0; c < CO_BLK; c++) {
                float* base = out + (size_t)(b * COUT + cog * CO_BLK + c) * OPLANE
                                  + (r + OPADV) * OSTR;
                base[0] = 0.f; base[31] = 0.f; base[32] = 0.f;
            }
        }
        return;
    }
    float acc[CO_BLK][2];
#pragma unroll
    for (int c = 0; c < CO_BLK; c++) {
        float bv = bias[cog * CO_BLK + c];
        acc[c][0] = bv; acc[c][1] = bv;
    }
    const float* inb = in + ((size_t)(b * CIN) * 32 + r) * 32 + ow0;
#pragma unroll 2
    for (int ci = 0; ci < CIN; ci++) {
        const float* rr = inb + (size_t)ci * 1024;
        float2 A[3], Bv[3];
#pragma unroll
        for (int kh = 0; kh < 3; kh++) {
            A[kh]  = *(const float2*)(rr + kh * 32);
            Bv[kh] = *(const float2*)(rr + kh * 32 + 2);
        }
        const float* wr = lw + ci * 9 * CO_BLK;
#pragma unroll
        for (int kh = 0; kh < 3; kh++) {
            float x0[3] = {A[kh].x, A[kh].y, Bv[kh].x};
            float x1[3] = {A[kh].y, Bv[kh].x, Bv[kh].y};
#pragma unroll
            for (int kw = 0; kw < 3; kw++) {
                float wv[CO_BLK];
                ldw<CO_BLK>(wr + (kh * 3 + kw) * CO_BLK, wv);
#pragma unroll
                for (int c = 0; c < CO_BLK; c++) {
                    acc[c][0] = fmaf(x0[kw], wv[c], acc[c][0]);
                    acc[c][1] = fmaf(x1[kw], wv[c], acc[c][1]);
                }
            }
        }
    }
    float* ob = out + (size_t)(b * COUT + cog * CO_BLK) * OPLANE
                    + (r + OPADV) * OSTR + ow0 + OPADH;
#pragma unroll
    for (int c = 0; c < CO_BLK; c++) {
        float v0 = acc[c][0]; v0 = (v0 >= 0.f) ? v0 : LRELU * v0;
        float v1 = acc[c][1]; v1 = (v1 >= 0.f) ? v1 : LRELU * v1;
        ob[(size_t)c * OPLANE] = v0;
        ob[(size_t)c * OPLANE + 1] = v1;
    }
}

// ======================= 1x1 conv -> NHWC latent =======================
// Writes latf[pos][64] (pos = b*900 + oh*30 + ow, interior only): each
// position's 64 dims are CONTIGUOUS (256 B).
__global__ __launch_bounds__(256)
void conv1nhwc_k(const float* __restrict__ in, const float* __restrict__ wt,
                 const float* __restrict__ bias, float* __restrict__ latf) {
    __shared__ __align__(16) float lw[32 * 4];
    const int b = blockIdx.x, cog = blockIdx.y;
    for (int i = threadIdx.x; i < 32 * 4; i += 256) {
        int row = i / 4, c = i - row * 4;
        lw[i] = wt[row * 64 + cog * 4 + c];
    }
    __syncthreads();

    const int px4 = threadIdx.x * 4;
    float acc[4][4];
#pragma unroll
    for (int c = 0; c < 4; c++) {
        float bv = bias[cog * 4 + c];
        acc[c][0] = bv; acc[c][1] = bv; acc[c][2] = bv; acc[c][3] = bv;
    }
#pragma unroll 4
    for (int ci = 0; ci < 32; ci++) {
        float4 x = *(const float4*)(in + (size_t)(b * 32 + ci) * 1024 + px4);
        float wv[4];
        ldw<4>(lw + ci * 4, wv);
#pragma unroll
        for (int c = 0; c < 4; c++) {
            acc[c][0] = fmaf(x.x, wv[c], acc[c][0]);
            acc[c][1] = fmaf(x.y, wv[c], acc[c][1]);
            acc[c][2] = fmaf(x.z, wv[c], acc[c][2]);
            acc[c][3] = fmaf(x.w, wv[c], acc[c][3]);
        }
    }
#pragma unroll
    for (int j = 0; j < 4; j++) {
        int pix = px4 + j;
        int row = pix >> 5, col = pix & 31;
        if (row >= 1 && row <= 30 && col >= 1 && col <= 30) {
            int pos = b * 900 + (row - 1) * 30 + (col - 1);
            float4 v;
            v.x = (acc[0][j] >= 0.f) ? acc[0][j] : LRELU * acc[0][j];
            v.y = (acc[1][j] >= 0.f) ? acc[1][j] : LRELU * acc[1][j];
            v.z = (acc[2][j] >= 0.f) ? acc[2][j] : LRELU * acc[2][j];
            v.w = (acc[3][j] >= 0.f) ? acc[3][j] : LRELU * acc[3][j];
            *(float4*)(latf + (size_t)pos * 64 + cog * 4) = v;
        }
    }
}

// ======================= d1 via code table (pad-2 output layout) ============
// out [64,32,30,(34)]: data cols 2..31, zero cols {1,32,33}.
__global__ __launch_bounds__(256)
void d1tab_k(const int* __restrict__ idxm, const float* __restrict__ U,
             const float* __restrict__ bias, float* __restrict__ out) {
    const int b = blockIdx.x, cog = blockIdx.y, rt = blockIdx.z;
    const int tx = threadIdx.x & 31, ty = threadIdx.x >> 5;
    const int r = rt * 8 + ty;
    if (r >= 30) return;
    if (tx >= 30) {
        if (tx == 31) {
#pragma unroll
            for (int c = 0; c < 16; c++) {
                float* base = out + (size_t)(b * 32 + cog * 16 + c) * 1020 + r * 34;
                base[1] = 0.f; base[32] = 0.f; base[33] = 0.f;
            }
        }
        return;
    }
    const int* im = idxm + b * 1024 + r * 32 + tx;
    float acc[16];
#pragma unroll
    for (int c = 0; c < 16; c++) acc[c] = bias[cog * 16 + c];
#pragma unroll
    for (int kh = 0; kh < 3; kh++) {
        int i0 = im[kh * 32 + 0];
        int i1 = im[kh * 32 + 1];
        int i2 = im[kh * 32 + 2];
        const float4* u0 = (const float4*)(U + ((size_t)i0 * 9 + kh * 3 + 0) * 32 + cog * 16);
        const float4* u1 = (const float4*)(U + ((size_t)i1 * 9 + kh * 3 + 1) * 32 + cog * 16);
        const float4* u2 = (const float4*)(U + ((size_t)i2 * 9 + kh * 3 + 2) * 32 + cog * 16);
#pragma unroll
        for (int q = 0; q < 4; q++) {
            float4 a = u0[q], bb = u1[q], cc = u2[q];
            acc[4*q+0] += (a.x + bb.x) + cc.x;
            acc[4*q+1] += (a.y + bb.y) + cc.y;
            acc[4*q+2] += (a.z + bb.z) + cc.z;
            acc[4*q+3] += (a.w + bb.w) + cc.w;
        }
    }
    float* ob = out + (size_t)(b * 32 + cog * 16) * 1020 + r * 34 + tx + 2;
#pragma unroll
    for (int c = 0; c < 16; c++) {
        float v = acc[c]; v = (v >= 0.f) ? v : LRELU * v;
        ob[(size_t)c * 1020] = v;
    }
}

// ======================= parity-fused convT k4 s2 (aligned float2 stores) ===
template<int CIN, int COUT, int CO_BLK, int HIN, int ISTR, int HOUT, int WOUT,
         int OPLANE, int OSTR, int OPADH, int NTX, int NT,
         int ZS_CH, int ZS_H, int ZS_STR, int ZC0, int ZC1, int ZC2,
         bool DO_TANH, bool DO_LOSS>
__global__ __launch_bounds__(256)
void convtf_k(const float* __restrict__ in, const float* __restrict__ wt,
              const float* __restrict__ bias, float* __restrict__ out,
              const float* __restrict__ loss, float* __restrict__ losstgt) {
    const int b = blockIdx.x, tid = threadIdx.x;
    const int NCOG = COUT / CO_BLK;
    int zz = blockIdx.z;
    if (zz >= NCOG * NT) {
        if (DO_LOSS) {
            if (b == 0 && tid == 0)
                losstgt[0] = 1.25f * loss[0] / (57600.f * 64.f);
            return;
        }
        int i = (zz - NCOG * NT) * 256 + tid;
        if (i >= ZS_CH * ZS_H * 3) return;
        int ch = i / (ZS_H * 3); int u = i - ch * ZS_H * 3;
        int r = u / 3, c3 = u - r * 3;
        int col = (c3 == 0) ? ZC0 : (c3 == 1) ? ZC1 : ZC2;
        out[((size_t)(b * ZS_CH + ch) * ZS_H + r) * ZS_STR + col] = 0.f;
        return;
    }
    const int cog = zz / NT, tile = zz - cog * NT;
    const int tlx = tile % NTX, tly = tile / NTX;

    __shared__ __align__(16) float lw[16 * CIN * CO_BLK];
    for (int i = tid; i < 16 * CIN * CO_BLK; i += 256) {
        int aq = i / (CIN * 4 * CO_BLK);
        int r1 = i - aq * (CIN * 4 * CO_BLK);
        int ci = r1 / (4 * CO_BLK);
        int u  = r1 - ci * (4 * CO_BLK);
        int pp = u / CO_BLK, c = u - pp * CO_BLK;
        int a = aq >> 1, q = aq & 1, py = pp >> 1, px = pp & 1;
        int tap = (py + 2 * a) * 4 + px + 2 * q;
        lw[i] = wt[((size_t)tap * CIN + ci) * COUT + cog * CO_BLK + c];
    }
    __syncthreads();

    const int SX = (WOUT + 1) >> 1, SY = (HOUT + 1) >> 1;
    const int sx0 = tlx * 32 + (tid & 15);
    const int sx1 = sx0 + 16;
    const int sy  = tly * 16 + (tid >> 4);
    const bool v0 = sx0 < SX, v1 = sx1 < SX;
    if (sy >= SY || !(v0 || v1)) return;

    const bool rvA = (sy < HIN);
    const bool rvB = (sy >= 1) && (sy <= HIN);

    float acc[2][4][CO_BLK];
#pragma unroll
    for (int s = 0; s < 2; s++)
#pragma unroll
        for (int o = 0; o < 4; o++)
#pragma unroll
            for (int c = 0; c < CO_BLK; c++)
                acc[s][o][c] = bias[cog * CO_BLK + c];

    const float* base = in + (size_t)(b * CIN) * HIN * ISTR;
#pragma unroll 2
    for (int ci = 0; ci < CIN; ci++) {
        const float* rowA = base + (size_t)ci * HIN * ISTR + (size_t)sy * ISTR;
        const float* rowB = rowA - ISTR;
        float rA0x = 0.f, rA0y = 0.f, rA1x = 0.f, rA1y = 0.f;
        float rB0x = 0.f, rB0y = 0.f, rB1x = 0.f, rB1y = 0.f;
        if (rvA) {
            if (v0) { rA0x = rowA[sx0]; rA0y = rowA[sx0 + 1]; }
            if (v1) { rA1x = rowA[sx1]; rA1y = rowA[sx1 + 1]; }
        }
        if (rvB) {
            if (v0) { rB0x = rowB[sx0]; rB0y = rowB[sx0 + 1]; }
            if (v1) { rB1x = rowB[sx1]; rB1y = rowB[sx1 + 1]; }
        }
#pragma unroll
        for (int a = 0; a < 2; a++) {
#pragma unroll
            for (int q = 0; q < 2; q++) {
                float iv0 = q ? (a ? rB0x : rA0x) : (a ? rB0y : rA0y);
                float iv1 = q ? (a ? rB1x : rA1x) : (a ? rB1y : rA1y);
                const float* wp = lw + (size_t)((a * 2 + q) * CIN + ci) * (4 * CO_BLK);
                float wv[4 * CO_BLK];
                ldw<4 * CO_BLK>(wp, wv);
#pragma unroll
                for (int o = 0; o < 4; o++)
#pragma unroll
                    for (int c = 0; c < CO_BLK; c++) {
                        acc[0][o][c] = fmaf(iv0, wv[o * CO_BLK + c], acc[0][o][c]);
                        acc[1][o][c] = fmaf(iv1, wv[o * CO_BLK + c], acc[1][o][c]);
                    }
            }
        }
    }
#pragma unroll
    for (int s = 0; s < 2; s++) {
        if (s ? !v1 : !v0) continue;
        const int sxx = s ? sx1 : sx0;
        const int ow = 2 * sxx;
        const bool full = (ow + 1) < WOUT;
#pragma unroll
        for (int py = 0; py < 2; py++) {
            int oh = 2 * sy + py;
            if (oh >= HOUT) continue;
            float* ob = out + (size_t)(b * COUT + cog * CO_BLK) * OPLANE
                            + (size_t)oh * OSTR + ow + OPADH;
#pragma unroll
            for (int c = 0; c < CO_BLK; c++) {
                float va = acc[s][py * 2 + 0][c];
                float vb = acc[s][py * 2 + 1][c];
                if (DO_TANH) { va = tanhf(va); vb = tanhf(vb); }
                else {
                    va = (va >= 0.f) ? va : LRELU * va;
                    vb = (vb >= 0.f) ? vb : LRELU * vb;
                }
                if ((OPADH & 1) == 0 && full) {
                    *(float2*)(ob + (size_t)c * OPLANE) = make_float2(va, vb);
                } else {
                    ob[(size_t)c * OPLANE] = va;
                    if (full) ob[(size_t)c * OPLANE + 1] = vb;
                }
            }
        }
    }
}

// ======================= VQ argmin (v7: k-blocked, NHWC, scalar codebook) ===
// Diagnosis r2-r5: the compiler ALWAYS re-loads the 64 latents inside the
// code loop (LICM hoists, allocator re-sinks across the back-edge; 4 source-
// level pinning attempts -> VGPR_Count 36-48, VALUBusy 33-40%, latency-bound
// at 74-84us). r1's LDS variant is DS-throughput-bound at ~70us (8x
// ds_read_b128/k/wave = 96 DS-cyc vs 156 VALU-cyc at 1:4 DS:SIMD ratio).
// Fix: STOP fighting the reload -- amortize it. Block the code loop by
// KTILE=8: reload L[16] once per outer iteration (4 dwordx4, L1-hit, NHWC
// contiguous), then 8 fully-unrolled codes x 64 FMA use it in straight-line
// code with no back-edge crossing. The asm memory clobber at the top of each
// outer iteration blocks LICM from hoisting the loads out (which would
// recreate the r5 situation). Worst case: 0.5 loads/code vs 4/code (r5) or
// 64/code (r2-r4). Codebook via wave-uniform s_load (scalar pipe, verified).
// grid (232, 8): x multiple of 8 keeps all 8 code chunks of a position block
// on one XCD (round-1 FETCH lesson). Confirming signal: VGPR_Count >= 80.
__global__ __launch_bounds__(256, 4)
void vq_argmin_k(const float* __restrict__ latf, const float* __restrict__ cb,
                 const float* __restrict__ hcbn,
                 unsigned long long* __restrict__ keys) {
    const int pb = blockIdx.x;
    if (pb >= 225) return;
    const int pos = pb * 256 + threadIdx.x;
    const int kbase = blockIdx.y * 64;

    const float4* lp = (const float4*)(latf + (size_t)pos * 64);

    float best = 3.4e38f;
    int   bi   = 0;
#pragma unroll 1
    for (int k0 = 0; k0 < 64; k0 += 8) {
        // Memory clobber: latent loads below cannot be hoisted above this
        // point (out of the outer loop) -- they stay in-body, where the
        // unrolled inner 8 uses them without crossing a back-edge.
        asm volatile("" ::: "memory");
        float4 L[16];
#pragma unroll
        for (int i = 0; i < 16; i++) L[i] = lp[i];
#pragma unroll
        for (int kk = 0; kk < 8; kk++) {
            const int k = kbase + k0 + kk;
            const float4* cp = (const float4*)(cb + (size_t)k * 64);
            float hn = hcbn[k];
            float a0 = 0.f, a1 = 0.f, a2 = 0.f, a3 = 0.f;
#pragma unroll
            for (int u = 0; u < 16; u++) {
                float4 c = cp[u];
                a0 = fmaf(L[u].x, c.x, a0);
                a1 = fmaf(L[u].y, c.y, a1);
                a2 = fmaf(L[u].z, c.z, a2);
                a3 = fmaf(L[u].w, c.w, a3);
            }
            float score = hn - ((a0 + a1) + (a2 + a3));
            if (score < best) { best = score; bi = k; }
        }
    }
    unsigned u = __float_as_uint(best);
    u = ((int)u < 0) ? ~u : (u | 0x80000000u);
    unsigned long long key = ((unsigned long long)u << 32) | (unsigned)bi;
    atomicMin(&keys[pos], key);
}

// ======================= VQ finalize: idx-map + loss =======================
__global__ __launch_bounds__(256)
void vq_finalize_k(const float* __restrict__ latf, const float* __restrict__ cb,
                   const unsigned long long* __restrict__ keys,
                   int* __restrict__ idxm, float* __restrict__ loss_acc, int B) {
    int gid = blockIdx.x * 256 + threadIdx.x;
    const int N = B * 900;
    float myloss = 0.f;
    if (gid < N) {
        int b = gid / 900, p = gid - b * 900;
        int oh = p / 30, ow = p - oh * 30;
        int pp = 33 + oh * 32 + ow;
        int idx = (int)(unsigned)(keys[gid] & 0xFFFFFFFFull);
        idxm[b * 1024 + pp] = idx;
        const float4* crow = (const float4*)(cb + (size_t)idx * 64);
        const float4* lrow = (const float4*)(latf + (size_t)gid * 64);
#pragma unroll
        for (int i = 0; i < 16; i++) {
            float4 cv = crow[i];
            float4 lv = lrow[i];
            float d0 = cv.x - lv.x, d1 = cv.y - lv.y;
            float d2 = cv.z - lv.z, d3 = cv.w - lv.w;
            myloss = fmaf(d0, d0, myloss);
            myloss = fmaf(d1, d1, myloss);
            myloss = fmaf(d2, d2, myloss);
            myloss = fmaf(d3, d3, myloss);
        }
    }
    __shared__ float red[256];
    red[threadIdx.x] = myloss;
    __syncthreads();
    for (int s = 128; s > 0; s >>= 1) {
        if ((int)threadIdx.x < s) red[threadIdx.x] += red[threadIdx.x + s];
        __syncthreads();
    }
    if (threadIdx.x == 0) atomicAdd(loss_acc, red[0]);
}

static inline int nblk(long long total) { return (int)((total + 255) / 256); }

extern "C" void kernel_launch(void* const* d_in, const int* in_sizes, int n_in,
                              void* d_out, int out_size, void* d_ws, size_t ws_size,
                              hipStream_t stream) {
    const float* x   = (const float*)d_in[0];
    const float* ew1 = (const float*)d_in[1];  const float* eb1 = (const float*)d_in[2];
    const float* ew2 = (const float*)d_in[3];  const float* eb2 = (const float*)d_in[4];
    const float* ew3 = (const float*)d_in[5];  const float* eb3 = (const float*)d_in[6];
    const float* ew4 = (const float*)d_in[7];  const float* eb4 = (const float*)d_in[8];
    const float* ew5 = (const float*)d_in[9];  const float* eb5 = (const float*)d_in[10];
    const float* dw1 = (const float*)d_in[11]; const float* db1 = (const float*)d_in[12];
    const float* dw2 = (const float*)d_in[13]; const float* db2 = (const float*)d_in[14];
    const float* dw3 = (const float*)d_in[15]; const float* db3 = (const float*)d_in[16];
    const float* dw4 = (const float*)d_in[17]; const float* db4 = (const float*)d_in[18];
    const float* cb  = (const float*)d_in[19];
    float* out = (float*)d_out;

    const int B = in_sizes[0] / (256 * 256);   // 64
    const int N = B * 900;                     // 57600

    // ---- workspace map (liveness-audited; peak 53.2 MB) ----
    // [0, 34,873,344):  e1out -> e3out -> latf[57600][64] -> d1out -> d3out
    // [34,873,344, 52,420,608): e2out -> e4out -> d2out[64,16,63,68]
    //   (keys/hcbn/idxm tucked at its tail, all dead before d2 writes)
    // [52,420,608+): loss | wtb | U   (alive across decoder; outside both)
    char* ws = (char*)d_ws;
    float* A     = (float*)(ws);
    float* Bb    = (float*)(ws + 34873344);
    float* d2out = (float*)(ws + 34873344);
    float* d3out = (float*)(ws);
    unsigned long long* keys = (unsigned long long*)(ws + 51126272);
    float* hcbn  = (float*)(ws + 51587072);
    int*   idxm  = (int*)(ws + 51589120);
    float* loss  = (float*)(ws + 52420608);
    float* wtb   = (float*)(ws + 52420864);
    float* U     = (float*)(ws + 52622592);
    float* ew1t = wtb;          float* ew2t = wtb + 128;
    float* ew3t = wtb + 2176;   float* ew4t = wtb + 10368;
    float* ew5t = wtb + 19584;  float* dw1t = wtb + 21632;
    float* dw2t = wtb + 40064;  float* dw3t = wtb + 48256;
    float* dw4t = wtb + 50304;

    prep_k<<<nblk(50945 + N + 64 * 124), 256, 0, stream>>>(
        ew1, ew2, ew3, ew4, ew5, dw1, dw2, dw3, dw4, wtb,
        cb, hcbn, keys, loss, idxm, N);
    ubuild_k<<<nblk(513 * 288), 256, 0, stream>>>(dw1t, cb, U);

    // ---- encoder ----
    convs2_k<1, 8, 8, 256, 256, 127, 127, 127 * 128, 128, 0, 4, 8, 32, 0>
        <<<dim3(B, 1, 32), 256, 0, stream>>>(x, ew1t, eb1, A);
    convs2_k<8, 16, 4, 127, 128, 62, 62, 62 * 64, 64, 0, 2, 4, 8, 0>
        <<<dim3(B, 4, 8), 256, 0, stream>>>(A, ew2t, eb2, Bb);
    convs2_k<16, 32, 4, 62, 64, 30, 30, 1024, 32, 1, 1, 2, 2, 32>
        <<<dim3(B, 8, 18), 256, 0, stream>>>(Bb, ew3t, eb3, A);
    conv3_k<32, 32, 4, 1024, 32, 1, 1, false>
        <<<dim3(B, 8, 2), 256, 0, stream>>>(A, ew4t, eb4, Bb);
    // 1x1 conv writes NHWC latent latf = A  [57600 pos][64 dims]
    conv1nhwc_k<<<dim3(B, 16, 1), 256, 0, stream>>>(Bb, ew5t, eb5, A);

    // ---- VQ ----
    vq_argmin_k<<<dim3(232, 8), 256, 0, stream>>>(A, cb, hcbn, keys);
    vq_finalize_k<<<nblk(N), 256, 0, stream>>>(A, cb, keys, idxm, loss, B);

    // ---- decoder ----
    // d1 via code table -> A [64,32,30,(34)] pad-2 (latf dead)
    d1tab_k<<<dim3(B, 2, 4), 256, 0, stream>>>(idxm, U, db1, A);
    // d2: A(+1) -> d2out [64,16,63,(68)] pad-2, zero cols {1,65,66}
    convtf_k<32, 16, 4, 30, 34, 63, 63, 63 * 68, 68, 2, 1, 2,
             16, 63, 68, 1, 65, 66, false, false>
        <<<dim3(B, 1, 20), 256, 0, stream>>>(A + 1, dw2t, db2, d2out,
                                             nullptr, nullptr);
    // d3: d2out(+1) -> d3out=ws+0 [64,8,129,(132)] pad-2, zero cols {1,131}
    convtf_k<16, 8, 8, 63, 68, 129, 129, 129 * 132, 132, 2, 3, 15,
             8, 129, 132, 1, 1, 131, false, false>
        <<<dim3(B, 1, 28), 256, 0, stream>>>(d2out + 1, dw3t, db3, d3out,
                                             nullptr, nullptr);
    // d4: d3out(+1) -> out [64,1,260,260], tanh, + loss-final slice
    convtf_k<8, 1, 1, 129, 132, 260, 260, 67600, 260, 0, 5, 45,
             0, 1, 1, 0, 0, 0, true, true>
        <<<dim3(B, 1, 46), 256, 0, stream>>>(d3out + 1, dw4t, db4, out, loss,
                                             out + (out_size - 1));
}

// Round 8
// 410.021 us; speedup vs baseline: 1.1675x; 1.1675x over previous
//
#include <hip/hip_runtime.h>
#include <hip/hip_bf16.h>
#include <math.h>

#define LRELU 0.01f

// ---------- vectorized LDS weight fetch ----------
template<int NW>
__device__ __forceinline__ void ldw(const float* p, float* w) {
    if constexpr (NW % 4 == 0) {
#pragma unroll
        for (int u = 0; u < NW / 4; u++) {
            float4 v = *(const float4*)(p + 4 * u);
            w[4*u] = v.x; w[4*u+1] = v.y; w[4*u+2] = v.z; w[4*u+3] = v.w;
        }
    } else {
#pragma unroll
        for (int c = 0; c < NW; c++) w[c] = p[c];
    }
}

// ======================= fused prep =======================
__device__ __forceinline__ void wfwd(const float* s, float* d, int CIN, int COUT,
                                     int KK, int i) {
    int co = i / (CIN * KK); int r = i - co * CIN * KK;
    int ci = r / KK; int t = r - ci * KK;
    d[(ci * KK + t) * COUT + co] = s[i];
}
__device__ __forceinline__ void wtr(const float* s, float* d, int CIN, int COUT,
                                    int KK, int i) {
    int ci = i / (COUT * KK); int r = i - ci * COUT * KK;
    int co = r / KK; int t = r - co * KK;
    d[(t * CIN + ci) * COUT + co] = s[i];
}
__global__ __launch_bounds__(256)
void prep_k(const float* e1, const float* e2, const float* e3, const float* e4,
            const float* e5, const float* d1, const float* d2, const float* d3,
            const float* d4, float* w, const float* cbp, float* hcbn,
            unsigned long long* keys, float* loss, int* idxm, int N) {
    int i = blockIdx.x * 256 + threadIdx.x;
    if      (i < 128)   wfwd(e1, w + 0,     1,  8, 16, i);
    else if (i < 2176)  wfwd(e2, w + 128,   8, 16, 16, i - 128);
    else if (i < 10368) wfwd(e3, w + 2176, 16, 32, 16, i - 2176);
    else if (i < 19584) wfwd(e4, w + 10368, 32, 32, 9, i - 10368);
    else if (i < 21632) wfwd(e5, w + 19584, 32, 64, 1, i - 19584);
    else if (i < 40064) wfwd(d1, w + 21632, 64, 32, 9, i - 21632);
    else if (i < 48256) wtr (d2, w + 40064, 32, 16, 16, i - 40064);
    else if (i < 50304) wtr (d3, w + 48256, 16,  8, 16, i - 48256);
    else if (i < 50432) wtr (d4, w + 50304,  8,  1, 16, i - 50304);
    else if (i < 50944) {
        int k = i - 50432;
        const float* c = cbp + k * 64;
        float s = 0.f;
#pragma unroll
        for (int d = 0; d < 64; d++) s = fmaf(c[d], c[d], s);
        hcbn[k] = 0.5f * s;
    } else if (i < 50944 + N) {
        keys[i - 50944] = 0xFFFFFFFFFFFFFFFFull;
    } else if (i == 50944 + N) {
        loss[0] = 0.f;
    } else if (i < 50945 + N + 64 * 124) {
        // idx-map padding frame = sentinel 512 (U[512] == 0)
        int j = i - (50945 + N);
        int b2 = j / 124, s = j - b2 * 124;
        int r, c;
        if (s < 32)      { r = 0;  c = s; }
        else if (s < 64) { r = 31; c = s - 32; }
        else { int u = s - 64; r = 1 + (u >> 1); c = (u & 1) * 31; }
        idxm[b2 * 1024 + r * 32 + c] = 512;
    }
}

// ======================= U table =======================
__global__ __launch_bounds__(256)
void ubuild_k(const float* __restrict__ w, const float* __restrict__ cb,
              float* __restrict__ U) {
    int g = blockIdx.x * 256 + threadIdx.x;
    if (g >= 513 * 288) return;
    if (g >= 512 * 288) { U[g] = 0.f; return; }
    int k = g / 288, rem = g - k * 288;
    const float* cr = cb + k * 64;
    float s = 0.f;
#pragma unroll 4
    for (int ci = 0; ci < 64; ci++)
        s = fmaf(w[ci * 288 + rem], cr[ci], s);
    U[g] = s;
}

// ======================= k4 s2 forward conv (+frame-zero slices) ============
template<int CIN, int COUT, int CO_BLK, int HIN, int ISTR, int HOUT, int WOUT,
         int OPLANE, int OSTR, int OPAD, int CB, int RB, int ZCONV, int ZF_CH>
__global__ __launch_bounds__(256)
void convs2_k(const float* __restrict__ in, const float* __restrict__ wt,
              const float* __restrict__ bias, float* __restrict__ out) {
    const int b = blockIdx.x, cog = blockIdx.y, tid = threadIdx.x;
    if (ZF_CH > 0 && (int)blockIdx.z >= ZCONV) {
        if (cog != 0) return;
        int i = ((int)blockIdx.z - ZCONV) * 256 + tid;
        if (i >= ZF_CH * 124) return;
        int ch = i / 124, s = i - ch * 124;
        int r, c;
        if (s < 32)      { r = 0;  c = s; }
        else if (s < 64) { r = 31; c = s - 32; }
        else { int u = s - 64; r = 1 + (u >> 1); c = (u & 1) * 31; }
        out[(size_t)(b * ZF_CH + ch) * 1024 + r * 32 + c] = 0.f;
        return;
    }
    __shared__ __align__(16) float lw[CIN * 16 * CO_BLK];
    for (int i = tid; i < CIN * 16 * CO_BLK; i += 256) {
        int row = i / CO_BLK, c = i - row * CO_BLK;
        lw[i] = wt[row * COUT + cog * CO_BLK + c];
    }
    __syncthreads();

    const int tz = blockIdx.z;
    const int cbi = tz / RB, rb = tz - cbi * RB;
    const int tx = tid & 15, ty = tid >> 4;
    const int ow0 = (cbi * 16 + tx) * 2;
    const int oh  = rb * 16 + ty;
    if (oh >= HOUT || ow0 >= WOUT) return;
    const bool p1v = (ow0 + 1) < WOUT;

    float acc[CO_BLK][2];
#pragma unroll
    for (int c = 0; c < CO_BLK; c++) {
        float bv = bias[cog * CO_BLK + c];
        acc[c][0] = bv; acc[c][1] = bv;
    }
    const float* inb = in + ((size_t)(b * CIN) * HIN + oh * 2) * ISTR + ow0 * 2;
#pragma unroll 2
    for (int ci = 0; ci < CIN; ci++) {
        const float* r = inb + (size_t)ci * HIN * ISTR;
        float4 a4[4]; float2 b2[4];
#pragma unroll
        for (int kh = 0; kh < 4; kh++) {
            a4[kh] = *(const float4*)(r + kh * ISTR);
            b2[kh] = p1v ? *(const float2*)(r + kh * ISTR + 4) : make_float2(0.f, 0.f);
        }
        const float* wr = lw + ci * 16 * CO_BLK;
#pragma unroll
        for (int kh = 0; kh < 4; kh++) {
            float x0[4] = {a4[kh].x, a4[kh].y, a4[kh].z, a4[kh].w};
            float x1[4] = {a4[kh].z, a4[kh].w, b2[kh].x, b2[kh].y};
#pragma unroll
            for (int kw = 0; kw < 4; kw++) {
                float wv[CO_BLK];
                ldw<CO_BLK>(wr + (kh * 4 + kw) * CO_BLK, wv);
#pragma unroll
                for (int c = 0; c < CO_BLK; c++) {
                    acc[c][0] = fmaf(x0[kw], wv[c], acc[c][0]);
                    acc[c][1] = fmaf(x1[kw], wv[c], acc[c][1]);
                }
            }
        }
    }
    float* ob = out + (size_t)(b * COUT + cog * CO_BLK) * OPLANE
                    + (oh + OPAD) * OSTR + ow0 + OPAD;
#pragma unroll
    for (int c = 0; c < CO_BLK; c++) {
        float v0 = acc[c][0]; v0 = (v0 >= 0.f) ? v0 : LRELU * v0;
        ob[(size_t)c * OPLANE] = v0;
        if (p1v) {
            float v1 = acc[c][1]; v1 = (v1 >= 0.f) ? v1 : LRELU * v1;
            ob[(size_t)c * OPLANE + 1] = v1;
        }
    }
}

// ======================= k3 s1 p1 conv =======================
template<int CIN, int COUT, int CO_BLK, int OPLANE, int OSTR, int OPADH, int OPADV,
         bool ZSIDE>
__global__ __launch_bounds__(256)
void conv3_k(const float* __restrict__ in, const float* __restrict__ wt,
             const float* __restrict__ bias, float* __restrict__ out) {
    const int b = blockIdx.x, cog = blockIdx.y, tid = threadIdx.x;
    __shared__ __align__(16) float lw[CIN * 9 * CO_BLK];
    for (int i = tid; i < CIN * 9 * CO_BLK; i += 256) {
        int row = i / CO_BLK, c = i - row * CO_BLK;
        lw[i] = wt[row * COUT + cog * CO_BLK + c];
    }
    __syncthreads();

    const int rb = blockIdx.z;
    const int tx = tid & 15, ty = tid >> 4;
    const int r = rb * 16 + ty;
    if (r >= 30) return;
    const int ow0 = tx * 2;
    if (tx == 15) {
        if (ZSIDE) {
#pragma unroll
            for (int c = 0; c < CO_BLK; c++) {
                float* base = out + (size_t)(b * COUT + cog * CO_BLK + c) * OPLANE
                                  + (r + OPADV) * OSTR;
                base[0] = 0.f; base[31] = 0.f; base[32] = 0.f;
            }
        }
        return;
    }
    float acc[CO_BLK][2];
#pragma unroll
    for (int c = 0; c < CO_BLK; c++) {
        float bv = bias[cog * CO_BLK + c];
        acc[c][0] = bv; acc[c][1] = bv;
    }
    const float* inb = in + ((size_t)(b * CIN) * 32 + r) * 32 + ow0;
#pragma unroll 2
    for (int ci = 0; ci < CIN; ci++) {
        const float* rr = inb + (size_t)ci * 1024;
        float2 A[3], Bv[3];
#pragma unroll
        for (int kh = 0; kh < 3; kh++) {
            A[kh]  = *(const float2*)(rr + kh * 32);
            Bv[kh] = *(const float2*)(rr + kh * 32 + 2);
        }
        const float* wr = lw + ci * 9 * CO_BLK;
#pragma unroll
        for (int kh = 0; kh < 3; kh++) {
            float x0[3] = {A[kh].x, A[kh].y, Bv[kh].x};
            float x1[3] = {A[kh].y, Bv[kh].x, Bv[kh].y};
#pragma unroll
            for (int kw = 0; kw < 3; kw++) {
                float wv[CO_BLK];
                ldw<CO_BLK>(wr + (kh * 3 + kw) * CO_BLK, wv);
#pragma unroll
                for (int c = 0; c < CO_BLK; c++) {
                    acc[c][0] = fmaf(x0[kw], wv[c], acc[c][0]);
                    acc[c][1] = fmaf(x1[kw], wv[c], acc[c][1]);
                }
            }
        }
    }
    float* ob = out + (size_t)(b * COUT + cog * CO_BLK) * OPLANE
                    + (r + OPADV) * OSTR + ow0 + OPADH;
#pragma unroll
    for (int c = 0; c < CO_BLK; c++) {
        float v0 = acc[c][0]; v0 = (v0 >= 0.f) ? v0 : LRELU * v0;
        float v1 = acc[c][1]; v1 = (v1 >= 0.f) ? v1 : LRELU * v1;
        ob[(size_t)c * OPLANE] = v0;
        ob[(size_t)c * OPLANE + 1] = v1;
    }
}

// ======================= 1x1 conv -> NHWC latent =======================
// Writes latf[pos][64] (pos = b*900 + oh*30 + ow, interior only): each
// position's 64 dims are CONTIGUOUS (256 B).
__global__ __launch_bounds__(256)
void conv1nhwc_k(const float* __restrict__ in, const float* __restrict__ wt,
                 const float* __restrict__ bias, float* __restrict__ latf) {
    __shared__ __align__(16) float lw[32 * 4];
    const int b = blockIdx.x, cog = blockIdx.y;
    for (int i = threadIdx.x; i < 32 * 4; i += 256) {
        int row = i / 4, c = i - row * 4;
        lw[i] = wt[row * 64 + cog * 4 + c];
    }
    __syncthreads();

    const int px4 = threadIdx.x * 4;
    float acc[4][4];
#pragma unroll
    for (int c = 0; c < 4; c++) {
        float bv = bias[cog * 4 + c];
        acc[c][0] = bv; acc[c][1] = bv; acc[c][2] = bv; acc[c][3] = bv;
    }
#pragma unroll 4
    for (int ci = 0; ci < 32; ci++) {
        float4 x = *(const float4*)(in + (size_t)(b * 32 + ci) * 1024 + px4);
        float wv[4];
        ldw<4>(lw + ci * 4, wv);
#pragma unroll
        for (int c = 0; c < 4; c++) {
            acc[c][0] = fmaf(x.x, wv[c], acc[c][0]);
            acc[c][1] = fmaf(x.y, wv[c], acc[c][1]);
            acc[c][2] = fmaf(x.z, wv[c], acc[c][2]);
            acc[c][3] = fmaf(x.w, wv[c], acc[c][3]);
        }
    }
#pragma unroll
    for (int j = 0; j < 4; j++) {
        int pix = px4 + j;
        int row = pix >> 5, col = pix & 31;
        if (row >= 1 && row <= 30 && col >= 1 && col <= 30) {
            int pos = b * 900 + (row - 1) * 30 + (col - 1);
            float4 v;
            v.x = (acc[0][j] >= 0.f) ? acc[0][j] : LRELU * acc[0][j];
            v.y = (acc[1][j] >= 0.f) ? acc[1][j] : LRELU * acc[1][j];
            v.z = (acc[2][j] >= 0.f) ? acc[2][j] : LRELU * acc[2][j];
            v.w = (acc[3][j] >= 0.f) ? acc[3][j] : LRELU * acc[3][j];
            *(float4*)(latf + (size_t)pos * 64 + cog * 4) = v;
        }
    }
}

// ======================= d1 via code table (pad-2 output layout) ============
// out [64,32,30,(34)]: data cols 2..31, zero cols {1,32,33}.
__global__ __launch_bounds__(256)
void d1tab_k(const int* __restrict__ idxm, const float* __restrict__ U,
             const float* __restrict__ bias, float* __restrict__ out) {
    const int b = blockIdx.x, cog = blockIdx.y, rt = blockIdx.z;
    const int tx = threadIdx.x & 31, ty = threadIdx.x >> 5;
    const int r = rt * 8 + ty;
    if (r >= 30) return;
    if (tx >= 30) {
        if (tx == 31) {
#pragma unroll
            for (int c = 0; c < 16; c++) {
                float* base = out + (size_t)(b * 32 + cog * 16 + c) * 1020 + r * 34;
                base[1] = 0.f; base[32] = 0.f; base[33] = 0.f;
            }
        }
        return;
    }
    const int* im = idxm + b * 1024 + r * 32 + tx;
    float acc[16];
#pragma unroll
    for (int c = 0; c < 16; c++) acc[c] = bias[cog * 16 + c];
#pragma unroll
    for (int kh = 0; kh < 3; kh++) {
        int i0 = im[kh * 32 + 0];
        int i1 = im[kh * 32 + 1];
        int i2 = im[kh * 32 + 2];
        const float4* u0 = (const float4*)(U + ((size_t)i0 * 9 + kh * 3 + 0) * 32 + cog * 16);
        const float4* u1 = (const float4*)(U + ((size_t)i1 * 9 + kh * 3 + 1) * 32 + cog * 16);
        const float4* u2 = (const float4*)(U + ((size_t)i2 * 9 + kh * 3 + 2) * 32 + cog * 16);
#pragma unroll
        for (int q = 0; q < 4; q++) {
            float4 a = u0[q], bb = u1[q], cc = u2[q];
            acc[4*q+0] += (a.x + bb.x) + cc.x;
            acc[4*q+1] += (a.y + bb.y) + cc.y;
            acc[4*q+2] += (a.z + bb.z) + cc.z;
            acc[4*q+3] += (a.w + bb.w) + cc.w;
        }
    }
    float* ob = out + (size_t)(b * 32 + cog * 16) * 1020 + r * 34 + tx + 2;
#pragma unroll
    for (int c = 0; c < 16; c++) {
        float v = acc[c]; v = (v >= 0.f) ? v : LRELU * v;
        ob[(size_t)c * 1020] = v;
    }
}

// ======================= parity-fused convT k4 s2 (aligned float2 stores) ===
template<int CIN, int COUT, int CO_BLK, int HIN, int ISTR, int HOUT, int WOUT,
         int OPLANE, int OSTR, int OPADH, int NTX, int NT,
         int ZS_CH, int ZS_H, int ZS_STR, int ZC0, int ZC1, int ZC2,
         bool DO_TANH, bool DO_LOSS>
__global__ __launch_bounds__(256)
void convtf_k(const float* __restrict__ in, const float* __restrict__ wt,
              const float* __restrict__ bias, float* __restrict__ out,
              const float* __restrict__ loss, float* __restrict__ losstgt) {
    const int b = blockIdx.x, tid = threadIdx.x;
    const int NCOG = COUT / CO_BLK;
    int zz = blockIdx.z;
    if (zz >= NCOG * NT) {
        if (DO_LOSS) {
            if (b == 0 && tid == 0)
                losstgt[0] = 1.25f * loss[0] / (57600.f * 64.f);
            return;
        }
        int i = (zz - NCOG * NT) * 256 + tid;
        if (i >= ZS_CH * ZS_H * 3) return;
        int ch = i / (ZS_H * 3); int u = i - ch * ZS_H * 3;
        int r = u / 3, c3 = u - r * 3;
        int col = (c3 == 0) ? ZC0 : (c3 == 1) ? ZC1 : ZC2;
        out[((size_t)(b * ZS_CH + ch) * ZS_H + r) * ZS_STR + col] = 0.f;
        return;
    }
    const int cog = zz / NT, tile = zz - cog * NT;
    const int tlx = tile % NTX, tly = tile / NTX;

    __shared__ __align__(16) float lw[16 * CIN * CO_BLK];
    for (int i = tid; i < 16 * CIN * CO_BLK; i += 256) {
        int aq = i / (CIN * 4 * CO_BLK);
        int r1 = i - aq * (CIN * 4 * CO_BLK);
        int ci = r1 / (4 * CO_BLK);
        int u  = r1 - ci * (4 * CO_BLK);
        int pp = u / CO_BLK, c = u - pp * CO_BLK;
        int a = aq >> 1, q = aq & 1, py = pp >> 1, px = pp & 1;
        int tap = (py + 2 * a) * 4 + px + 2 * q;
        lw[i] = wt[((size_t)tap * CIN + ci) * COUT + cog * CO_BLK + c];
    }
    __syncthreads();

    const int SX = (WOUT + 1) >> 1, SY = (HOUT + 1) >> 1;
    const int sx0 = tlx * 32 + (tid & 15);
    const int sx1 = sx0 + 16;
    const int sy  = tly * 16 + (tid >> 4);
    const bool v0 = sx0 < SX, v1 = sx1 < SX;
    if (sy >= SY || !(v0 || v1)) return;

    const bool rvA = (sy < HIN);
    const bool rvB = (sy >= 1) && (sy <= HIN);

    float acc[2][4][CO_BLK];
#pragma unroll
    for (int s = 0; s < 2; s++)
#pragma unroll
        for (int o = 0; o < 4; o++)
#pragma unroll
            for (int c = 0; c < CO_BLK; c++)
                acc[s][o][c] = bias[cog * CO_BLK + c];

    const float* base = in + (size_t)(b * CIN) * HIN * ISTR;
#pragma unroll 2
    for (int ci = 0; ci < CIN; ci++) {
        const float* rowA = base + (size_t)ci * HIN * ISTR + (size_t)sy * ISTR;
        const float* rowB = rowA - ISTR;
        float rA0x = 0.f, rA0y = 0.f, rA1x = 0.f, rA1y = 0.f;
        float rB0x = 0.f, rB0y = 0.f, rB1x = 0.f, rB1y = 0.f;
        if (rvA) {
            if (v0) { rA0x = rowA[sx0]; rA0y = rowA[sx0 + 1]; }
            if (v1) { rA1x = rowA[sx1]; rA1y = rowA[sx1 + 1]; }
        }
        if (rvB) {
            if (v0) { rB0x = rowB[sx0]; rB0y = rowB[sx0 + 1]; }
            if (v1) { rB1x = rowB[sx1]; rB1y = rowB[sx1 + 1]; }
        }
#pragma unroll
        for (int a = 0; a < 2; a++) {
#pragma unroll
            for (int q = 0; q < 2; q++) {
                float iv0 = q ? (a ? rB0x : rA0x) : (a ? rB0y : rA0y);
                float iv1 = q ? (a ? rB1x : rA1x) : (a ? rB1y : rA1y);
                const float* wp = lw + (size_t)((a * 2 + q) * CIN + ci) * (4 * CO_BLK);
                float wv[4 * CO_BLK];
                ldw<4 * CO_BLK>(wp, wv);
#pragma unroll
                for (int o = 0; o < 4; o++)
#pragma unroll
                    for (int c = 0; c < CO_BLK; c++) {
                        acc[0][o][c] = fmaf(iv0, wv[o * CO_BLK + c], acc[0][o][c]);
                        acc[1][o][c] = fmaf(iv1, wv[o * CO_BLK + c], acc[1][o][c]);
                    }
            }
        }
    }
#pragma unroll
    for (int s = 0; s < 2; s++) {
        if (s ? !v1 : !v0) continue;
        const int sxx = s ? sx1 : sx0;
        const int ow = 2 * sxx;
        const bool full = (ow + 1) < WOUT;
#pragma unroll
        for (int py = 0; py < 2; py++) {
            int oh = 2 * sy + py;
            if (oh >= HOUT) continue;
            float* ob = out + (size_t)(b * COUT + cog * CO_BLK) * OPLANE
                            + (size_t)oh * OSTR + ow + OPADH;
#pragma unroll
            for (int c = 0; c < CO_BLK; c++) {
                float va = acc[s][py * 2 + 0][c];
                float vb = acc[s][py * 2 + 1][c];
                if (DO_TANH) { va = tanhf(va); vb = tanhf(vb); }
                else {
                    va = (va >= 0.f) ? va : LRELU * va;
                    vb = (vb >= 0.f) ? vb : LRELU * vb;
                }
                if ((OPADH & 1) == 0 && full) {
                    *(float2*)(ob + (size_t)c * OPLANE) = make_float2(va, vb);
                } else {
                    ob[(size_t)c * OPLANE] = va;
                    if (full) ob[(size_t)c * OPLANE + 1] = vb;
                }
            }
        }
    }
}

// ======================= VQ argmin (v8b: r0 structure + DPP reduce) =========
// Same as round-7 theory; fix = dpp ctrl as TEMPLATE param (the builtin
// requires a constant-integer ctrl -- runtime param failed to compile).
// Structure: LDS-broadcast codebook (the only structure that dodges the
// compiler's latent-reload pathology), r0's 4pos x 16dim tiling (4 b128
// LDS reads/wave-k serving 64 positions), DPP quad_perm adds instead of
// ds_swizzle shuffles (pure VALU, dq=tid&3 = lane-within-quad), NHWC
// latent loads, grid.x=232 XCD-aligned. Model: DS ~40us, VALU ~41us.
template<int CTRL>
__device__ __forceinline__ float dpp_qp_add(float x) {
    int y = __builtin_amdgcn_update_dpp(0, __float_as_int(x), CTRL, 0xF, 0xF, true);
    return x + __int_as_float(y);
}

__global__ __launch_bounds__(256, 4)
void vq_argmin_k(const float* __restrict__ latf, const float* __restrict__ cb,
                 const float* __restrict__ hcbn,
                 unsigned long long* __restrict__ keys) {
    const int pb = blockIdx.x;
    if (pb >= 225) return;
    __shared__ float4 scb4[1024];   // 64 codes x 64 dims
    __shared__ float  shn[64];
    const int tid = threadIdx.x;
    const int dq  = tid & 3;        // dim quarter: dims [dq*16, dq*16+16)
    const int pg  = tid >> 2;       // 0..63
    const int kbase = blockIdx.y * 64;
    const int posbase = pb * 256;

    const float4* src = (const float4*)(cb + (size_t)kbase * 64);
#pragma unroll
    for (int i = 0; i < 4; i++) scb4[tid + 256 * i] = src[tid + 256 * i];
    if (tid < 64) shn[tid] = hcbn[kbase + tid];

    // 4 positions x 16 dims, NHWC-contiguous (4 float4 per position)
    float4 L[4][4];
    int pidx[4];
#pragma unroll
    for (int j = 0; j < 4; j++) {
        int pos = posbase + pg + 64 * j;
        pidx[j] = pos;
        const float4* lp = (const float4*)(latf + (size_t)pos * 64 + dq * 16);
#pragma unroll
        for (int u = 0; u < 4; u++) L[j][u] = lp[u];
    }
    __syncthreads();

    float best[4] = {3.4e38f, 3.4e38f, 3.4e38f, 3.4e38f};
    int   bi[4]   = {0, 0, 0, 0};
#pragma unroll 2
    for (int k = 0; k < 64; k++) {
        float4 c0 = scb4[(k << 4) + (dq << 2) + 0];
        float4 c1 = scb4[(k << 4) + (dq << 2) + 1];
        float4 c2 = scb4[(k << 4) + (dq << 2) + 2];
        float4 c3 = scb4[(k << 4) + (dq << 2) + 3];
        float hn = shn[k];
#pragma unroll
        for (int j = 0; j < 4; j++) {
            float a0 = 0.f, a1 = 0.f;
            a0 = fmaf(L[j][0].x, c0.x, a0); a1 = fmaf(L[j][0].y, c0.y, a1);
            a0 = fmaf(L[j][0].z, c0.z, a0); a1 = fmaf(L[j][0].w, c0.w, a1);
            a0 = fmaf(L[j][1].x, c1.x, a0); a1 = fmaf(L[j][1].y, c1.y, a1);
            a0 = fmaf(L[j][1].z, c1.z, a0); a1 = fmaf(L[j][1].w, c1.w, a1);
            a0 = fmaf(L[j][2].x, c2.x, a0); a1 = fmaf(L[j][2].y, c2.y, a1);
            a0 = fmaf(L[j][2].z, c2.z, a0); a1 = fmaf(L[j][2].w, c2.w, a1);
            a0 = fmaf(L[j][3].x, c3.x, a0); a1 = fmaf(L[j][3].y, c3.y, a1);
            a0 = fmaf(L[j][3].z, c3.z, a0); a1 = fmaf(L[j][3].w, c3.w, a1);
            float dot = a0 + a1;
            float t   = dpp_qp_add<0xB1>(dot);  // quad_perm [1,0,3,2]: +lane^1
            float tot = dpp_qp_add<0x4E>(t);    // quad_perm [2,3,0,1]: +lane^2
            float score = hn - tot;
            if (score < best[j]) { best[j] = score; bi[j] = kbase + k; }
        }
    }
    if (dq == 0) {
#pragma unroll
        for (int j = 0; j < 4; j++) {
            unsigned u = __float_as_uint(best[j]);
            u = ((int)u < 0) ? ~u : (u | 0x80000000u);
            unsigned long long key = ((unsigned long long)u << 32) | (unsigned)bi[j];
            atomicMin(&keys[pidx[j]], key);
        }
    }
}

// ======================= VQ finalize: idx-map + loss =======================
__global__ __launch_bounds__(256)
void vq_finalize_k(const float* __restrict__ latf, const float* __restrict__ cb,
                   const unsigned long long* __restrict__ keys,
                   int* __restrict__ idxm, float* __restrict__ loss_acc, int B) {
    int gid = blockIdx.x * 256 + threadIdx.x;
    const int N = B * 900;
    float myloss = 0.f;
    if (gid < N) {
        int b = gid / 900, p = gid - b * 900;
        int oh = p / 30, ow = p - oh * 30;
        int pp = 33 + oh * 32 + ow;
        int idx = (int)(unsigned)(keys[gid] & 0xFFFFFFFFull);
        idxm[b * 1024 + pp] = idx;
        const float4* crow = (const float4*)(cb + (size_t)idx * 64);
        const float4* lrow = (const float4*)(latf + (size_t)gid * 64);
#pragma unroll
        for (int i = 0; i < 16; i++) {
            float4 cv = crow[i];
            float4 lv = lrow[i];
            float d0 = cv.x - lv.x, d1 = cv.y - lv.y;
            float d2 = cv.z - lv.z, d3 = cv.w - lv.w;
            myloss = fmaf(d0, d0, myloss);
            myloss = fmaf(d1, d1, myloss);
            myloss = fmaf(d2, d2, myloss);
            myloss = fmaf(d3, d3, myloss);
        }
    }
    __shared__ float red[256];
    red[threadIdx.x] = myloss;
    __syncthreads();
    for (int s = 128; s > 0; s >>= 1) {
        if ((int)threadIdx.x < s) red[threadIdx.x] += red[threadIdx.x + s];
        __syncthreads();
    }
    if (threadIdx.x == 0) atomicAdd(loss_acc, red[0]);
}

static inline int nblk(long long total) { return (int)((total + 255) / 256); }

extern "C" void kernel_launch(void* const* d_in, const int* in_sizes, int n_in,
                              void* d_out, int out_size, void* d_ws, size_t ws_size,
                              hipStream_t stream) {
    const float* x   = (const float*)d_in[0];
    const float* ew1 = (const float*)d_in[1];  const float* eb1 = (const float*)d_in[2];
    const float* ew2 = (const float*)d_in[3];  const float* eb2 = (const float*)d_in[4];
    const float* ew3 = (const float*)d_in[5];  const float* eb3 = (const float*)d_in[6];
    const float* ew4 = (const float*)d_in[7];  const float* eb4 = (const float*)d_in[8];
    const float* ew5 = (const float*)d_in[9];  const float* eb5 = (const float*)d_in[10];
    const float* dw1 = (const float*)d_in[11]; const float* db1 = (const float*)d_in[12];
    const float* dw2 = (const float*)d_in[13]; const float* db2 = (const float*)d_in[14];
    const float* dw3 = (const float*)d_in[15]; const float* db3 = (const float*)d_in[16];
    const float* dw4 = (const float*)d_in[17]; const float* db4 = (const float*)d_in[18];
    const float* cb  = (const float*)d_in[19];
    float* out = (float*)d_out;

    const int B = in_sizes[0] / (256 * 256);   // 64
    const int N = B * 900;                     // 57600

    // ---- workspace map (liveness-audited; peak 53.2 MB) ----
    // [0, 34,873,344):  e1out -> e3out -> latf[57600][64] -> d1out -> d3out
    // [34,873,344, 52,420,608): e2out -> e4out -> d2out[64,16,63,68]
    //   (keys/hcbn/idxm tucked at its tail, all dead before d2 writes)
    // [52,420,608+): loss | wtb | U   (alive across decoder; outside both)
    char* ws = (char*)d_ws;
    float* A     = (float*)(ws);
    float* Bb    = (float*)(ws + 34873344);
    float* d2out = (float*)(ws + 34873344);
    float* d3out = (float*)(ws);
    unsigned long long* keys = (unsigned long long*)(ws + 51126272);
    float* hcbn  = (float*)(ws + 51587072);
    int*   idxm  = (int*)(ws + 51589120);
    float* loss  = (float*)(ws + 52420608);
    float* wtb   = (float*)(ws + 52420864);
    float* U     = (float*)(ws + 52622592);
    float* ew1t = wtb;          float* ew2t = wtb + 128;
    float* ew3t = wtb + 2176;   float* ew4t = wtb + 10368;
    float* ew5t = wtb + 19584;  float* dw1t = wtb + 21632;
    float* dw2t = wtb + 40064;  float* dw3t = wtb + 48256;
    float* dw4t = wtb + 50304;

    prep_k<<<nblk(50945 + N + 64 * 124), 256, 0, stream>>>(
        ew1, ew2, ew3, ew4, ew5, dw1, dw2, dw3, dw4, wtb,
        cb, hcbn, keys, loss, idxm, N);
    ubuild_k<<<nblk(513 * 288), 256, 0, stream>>>(dw1t, cb, U);

    // ---- encoder ----
    convs2_k<1, 8, 8, 256, 256, 127, 127, 127 * 128, 128, 0, 4, 8, 32, 0>
        <<<dim3(B, 1, 32), 256, 0, stream>>>(x, ew1t, eb1, A);
    convs2_k<8, 16, 4, 127, 128, 62, 62, 62 * 64, 64, 0, 2, 4, 8, 0>
        <<<dim3(B, 4, 8), 256, 0, stream>>>(A, ew2t, eb2, Bb);
    convs2_k<16, 32, 4, 62, 64, 30, 30, 1024, 32, 1, 1, 2, 2, 32>
        <<<dim3(B, 8, 18), 256, 0, stream>>>(Bb, ew3t, eb3, A);
    conv3_k<32, 32, 4, 1024, 32, 1, 1, false>
        <<<dim3(B, 8, 2), 256, 0, stream>>>(A, ew4t, eb4, Bb);
    // 1x1 conv writes NHWC latent latf = A  [57600 pos][64 dims]
    conv1nhwc_k<<<dim3(B, 16, 1), 256, 0, stream>>>(Bb, ew5t, eb5, A);

    // ---- VQ ----
    vq_argmin_k<<<dim3(232, 8), 256, 0, stream>>>(A, cb, hcbn, keys);
    vq_finalize_k<<<nblk(N), 256, 0, stream>>>(A, cb, keys, idxm, loss, B);

    // ---- decoder ----
    // d1 via code table -> A [64,32,30,(34)] pad-2 (latf dead)
    d1tab_k<<<dim3(B, 2, 4), 256, 0, stream>>>(idxm, U, db1, A);
    // d2: A(+1) -> d2out [64,16,63,(68)] pad-2, zero cols {1,65,66}
    convtf_k<32, 16, 4, 30, 34, 63, 63, 63 * 68, 68, 2, 1, 2,
             16, 63, 68, 1, 65, 66, false, false>
        <<<dim3(B, 1, 20), 256, 0, stream>>>(A + 1, dw2t, db2, d2out,
                                             nullptr, nullptr);
    // d3: d2out(+1) -> d3out=ws+0 [64,8,129,(132)] pad-2, zero cols {1,131}
    convtf_k<16, 8, 8, 63, 68, 129, 129, 129 * 132, 132, 2, 3, 15,
             8, 129, 132, 1, 1, 131, false, false>
        <<<dim3(B, 1, 28), 256, 0, stream>>>(d2out + 1, dw3t, db3, d3out,
                                             nullptr, nullptr);
    // d4: d3out(+1) -> out [64,1,260,260], tanh, + loss-final slice
    convtf_k<8, 1, 1, 129, 132, 260, 260, 67600, 260, 0, 5, 45,
             0, 1, 1, 0, 0, 0, true, true>
        <<<dim3(B, 1, 46), 256, 0, stream>>>(d3out + 1, dw4t, db4, out, loss,
                                             out + (out_size - 1));
}

// Round 9
// 393.818 us; speedup vs baseline: 1.2155x; 1.0411x over previous
//
#include <hip/hip_runtime.h>
#include <hip/hip_bf16.h>
#include <math.h>

#define LRELU 0.01f

// ---------- vectorized LDS weight fetch ----------
template<int NW>
__device__ __forceinline__ void ldw(const float* p, float* w) {
    if constexpr (NW % 4 == 0) {
#pragma unroll
        for (int u = 0; u < NW / 4; u++) {
            float4 v = *(const float4*)(p + 4 * u);
            w[4*u] = v.x; w[4*u+1] = v.y; w[4*u+2] = v.z; w[4*u+3] = v.w;
        }
    } else {
#pragma unroll
        for (int c = 0; c < NW; c++) w[c] = p[c];
    }
}

// ======================= fused prep =======================
__device__ __forceinline__ void wfwd(const float* s, float* d, int CIN, int COUT,
                                     int KK, int i) {
    int co = i / (CIN * KK); int r = i - co * CIN * KK;
    int ci = r / KK; int t = r - ci * KK;
    d[(ci * KK + t) * COUT + co] = s[i];
}
__device__ __forceinline__ void wtr(const float* s, float* d, int CIN, int COUT,
                                    int KK, int i) {
    int ci = i / (COUT * KK); int r = i - ci * COUT * KK;
    int co = r / KK; int t = r - co * KK;
    d[(t * CIN + ci) * COUT + co] = s[i];
}
__global__ __launch_bounds__(256)
void prep_k(const float* e1, const float* e2, const float* e3, const float* e4,
            const float* e5, const float* d1, const float* d2, const float* d3,
            const float* d4, float* w, const float* cbp, float* hcbn,
            unsigned long long* keys, float* loss, int* idxm, int N) {
    int i = blockIdx.x * 256 + threadIdx.x;
    if      (i < 128)   wfwd(e1, w + 0,     1,  8, 16, i);
    else if (i < 2176)  wfwd(e2, w + 128,   8, 16, 16, i - 128);
    else if (i < 10368) wfwd(e3, w + 2176, 16, 32, 16, i - 2176);
    else if (i < 19584) wfwd(e4, w + 10368, 32, 32, 9, i - 10368);
    else if (i < 21632) wfwd(e5, w + 19584, 32, 64, 1, i - 19584);
    else if (i < 40064) wfwd(d1, w + 21632, 64, 32, 9, i - 21632);
    else if (i < 48256) wtr (d2, w + 40064, 32, 16, 16, i - 40064);
    else if (i < 50304) wtr (d3, w + 48256, 16,  8, 16, i - 48256);
    else if (i < 50432) wtr (d4, w + 50304,  8,  1, 16, i - 50304);
    else if (i < 50944) {
        int k = i - 50432;
        const float* c = cbp + k * 64;
        float s = 0.f;
#pragma unroll
        for (int d = 0; d < 64; d++) s = fmaf(c[d], c[d], s);
        hcbn[k] = 0.5f * s;
    } else if (i < 50944 + N) {
        keys[i - 50944] = 0xFFFFFFFFFFFFFFFFull;
    } else if (i == 50944 + N) {
        loss[0] = 0.f;
    } else if (i < 50945 + N + 64 * 124) {
        // idx-map padding frame = sentinel 512 (U[512] == 0)
        int j = i - (50945 + N);
        int b2 = j / 124, s = j - b2 * 124;
        int r, c;
        if (s < 32)      { r = 0;  c = s; }
        else if (s < 64) { r = 31; c = s - 32; }
        else { int u = s - 64; r = 1 + (u >> 1); c = (u & 1) * 31; }
        idxm[b2 * 1024 + r * 32 + c] = 512;
    }
}

// ======================= U table =======================
__global__ __launch_bounds__(256)
void ubuild_k(const float* __restrict__ w, const float* __restrict__ cb,
              float* __restrict__ U) {
    int g = blockIdx.x * 256 + threadIdx.x;
    if (g >= 513 * 288) return;
    if (g >= 512 * 288) { U[g] = 0.f; return; }
    int k = g / 288, rem = g - k * 288;
    const float* cr = cb + k * 64;
    float s = 0.f;
#pragma unroll 4
    for (int ci = 0; ci < 64; ci++)
        s = fmaf(w[ci * 288 + rem], cr[ci], s);
    U[g] = s;
}

// ======================= k4 s2 forward conv (+frame-zero slices) ============
template<int CIN, int COUT, int CO_BLK, int HIN, int ISTR, int HOUT, int WOUT,
         int OPLANE, int OSTR, int OPAD, int CB, int RB, int ZCONV, int ZF_CH>
__global__ __launch_bounds__(256)
void convs2_k(const float* __restrict__ in, const float* __restrict__ wt,
              const float* __restrict__ bias, float* __restrict__ out) {
    const int b = blockIdx.x, cog = blockIdx.y, tid = threadIdx.x;
    if (ZF_CH > 0 && (int)blockIdx.z >= ZCONV) {
        if (cog != 0) return;
        int i = ((int)blockIdx.z - ZCONV) * 256 + tid;
        if (i >= ZF_CH * 124) return;
        int ch = i / 124, s = i - ch * 124;
        int r, c;
        if (s < 32)      { r = 0;  c = s; }
        else if (s < 64) { r = 31; c = s - 32; }
        else { int u = s - 64; r = 1 + (u >> 1); c = (u & 1) * 31; }
        out[(size_t)(b * ZF_CH + ch) * 1024 + r * 32 + c] = 0.f;
        return;
    }
    __shared__ __align__(16) float lw[CIN * 16 * CO_BLK];
    for (int i = tid; i < CIN * 16 * CO_BLK; i += 256) {
        int row = i / CO_BLK, c = i - row * CO_BLK;
        lw[i] = wt[row * COUT + cog * CO_BLK + c];
    }
    __syncthreads();

    const int tz = blockIdx.z;
    const int cbi = tz / RB, rb = tz - cbi * RB;
    const int tx = tid & 15, ty = tid >> 4;
    const int ow0 = (cbi * 16 + tx) * 2;
    const int oh  = rb * 16 + ty;
    if (oh >= HOUT || ow0 >= WOUT) return;
    const bool p1v = (ow0 + 1) < WOUT;

    float acc[CO_BLK][2];
#pragma unroll
    for (int c = 0; c < CO_BLK; c++) {
        float bv = bias[cog * CO_BLK + c];
        acc[c][0] = bv; acc[c][1] = bv;
    }
    const float* inb = in + ((size_t)(b * CIN) * HIN + oh * 2) * ISTR + ow0 * 2;
#pragma unroll 2
    for (int ci = 0; ci < CIN; ci++) {
        const float* r = inb + (size_t)ci * HIN * ISTR;
        float4 a4[4]; float2 b2[4];
#pragma unroll
        for (int kh = 0; kh < 4; kh++) {
            a4[kh] = *(const float4*)(r + kh * ISTR);
            b2[kh] = p1v ? *(const float2*)(r + kh * ISTR + 4) : make_float2(0.f, 0.f);
        }
        const float* wr = lw + ci * 16 * CO_BLK;
#pragma unroll
        for (int kh = 0; kh < 4; kh++) {
            float x0[4] = {a4[kh].x, a4[kh].y, a4[kh].z, a4[kh].w};
            float x1[4] = {a4[kh].z, a4[kh].w, b2[kh].x, b2[kh].y};
#pragma unroll
            for (int kw = 0; kw < 4; kw++) {
                float wv[CO_BLK];
                ldw<CO_BLK>(wr + (kh * 4 + kw) * CO_BLK, wv);
#pragma unroll
                for (int c = 0; c < CO_BLK; c++) {
                    acc[c][0] = fmaf(x0[kw], wv[c], acc[c][0]);
                    acc[c][1] = fmaf(x1[kw], wv[c], acc[c][1]);
                }
            }
        }
    }
    float* ob = out + (size_t)(b * COUT + cog * CO_BLK) * OPLANE
                    + (oh + OPAD) * OSTR + ow0 + OPAD;
#pragma unroll
    for (int c = 0; c < CO_BLK; c++) {
        float v0 = acc[c][0]; v0 = (v0 >= 0.f) ? v0 : LRELU * v0;
        ob[(size_t)c * OPLANE] = v0;
        if (p1v) {
            float v1 = acc[c][1]; v1 = (v1 >= 0.f) ? v1 : LRELU * v1;
            ob[(size_t)c * OPLANE + 1] = v1;
        }
    }
}

// ======================= k3 s1 p1 conv =======================
template<int CIN, int COUT, int CO_BLK, int OPLANE, int OSTR, int OPADH, int OPADV,
         bool ZSIDE>
__global__ __launch_bounds__(256)
void conv3_k(const float* __restrict__ in, const float* __restrict__ wt,
             const float* __restrict__ bias, float* __restrict__ out) {
    const int b = blockIdx.x, cog = blockIdx.y, tid = threadIdx.x;
    __shared__ __align__(16) float lw[CIN * 9 * CO_BLK];
    for (int i = tid; i < CIN * 9 * CO_BLK; i += 256) {
        int row = i / CO_BLK, c = i - row * CO_BLK;
        lw[i] = wt[row * COUT + cog * CO_BLK + c];
    }
    __syncthreads();

    const int rb = blockIdx.z;
    const int tx = tid & 15, ty = tid >> 4;
    const int r = rb * 16 + ty;
    if (r >= 30) return;
    const int ow0 = tx * 2;
    if (tx == 15) {
        if (ZSIDE) {
#pragma unroll
            for (int c = 0; c < CO_BLK; c++) {
                float* base = out + (size_t)(b * COUT + cog * CO_BLK + c) * OPLANE
                                  + (r + OPADV) * OSTR;
                base[0] = 0.f; base[31] = 0.f; base[32] = 0.f;
            }
        }
        return;
    }
    float acc[CO_BLK][2];
#pragma unroll
    for (int c = 0; c < CO_BLK; c++) {
        float bv = bias[cog * CO_BLK + c];
        acc[c][0] = bv; acc[c][1] = bv;
    }
    const float* inb = in + ((size_t)(b * CIN) * 32 + r) * 32 + ow0;
#pragma unroll 2
    for (int ci = 0; ci < CIN; ci++) {
        const float* rr = inb + (size_t)ci * 1024;
        float2 A[3], Bv[3];
#pragma unroll
        for (int kh = 0; kh < 3; kh++) {
            A[kh]  = *(const float2*)(rr + kh * 32);
            Bv[kh] = *(const float2*)(rr + kh * 32 + 2);
        }
        const float* wr = lw + ci * 9 * CO_BLK;
#pragma unroll
        for (int kh = 0; kh < 3; kh++) {
            float x0[3] = {A[kh].x, A[kh].y, Bv[kh].x};
            float x1[3] = {A[kh].y, Bv[kh].x, Bv[kh].y};
#pragma unroll
            for (int kw = 0; kw < 3; kw++) {
                float wv[CO_BLK];
                ldw<CO_BLK>(wr + (kh * 3 + kw) * CO_BLK, wv);
#pragma unroll
                for (int c = 0; c < CO_BLK; c++) {
                    acc[c][0] = fmaf(x0[kw], wv[c], acc[c][0]);
                    acc[c][1] = fmaf(x1[kw], wv[c], acc[c][1]);
                }
            }
        }
    }
    float* ob = out + (size_t)(b * COUT + cog * CO_BLK) * OPLANE
                    + (r + OPADV) * OSTR + ow0 + OPADH;
#pragma unroll
    for (int c = 0; c < CO_BLK; c++) {
        float v0 = acc[c][0]; v0 = (v0 >= 0.f) ? v0 : LRELU * v0;
        float v1 = acc[c][1]; v1 = (v1 >= 0.f) ? v1 : LRELU * v1;
        ob[(size_t)c * OPLANE] = v0;
        ob[(size_t)c * OPLANE + 1] = v1;
    }
}

// ======================= 1x1 conv -> NHWC latent =======================
// Writes latf[pos][64] (pos = b*900 + oh*30 + ow, interior only): each
// position's 64 dims are CONTIGUOUS (256 B).
__global__ __launch_bounds__(256)
void conv1nhwc_k(const float* __restrict__ in, const float* __restrict__ wt,
                 const float* __restrict__ bias, float* __restrict__ latf) {
    __shared__ __align__(16) float lw[32 * 4];
    const int b = blockIdx.x, cog = blockIdx.y;
    for (int i = threadIdx.x; i < 32 * 4; i += 256) {
        int row = i / 4, c = i - row * 4;
        lw[i] = wt[row * 64 + cog * 4 + c];
    }
    __syncthreads();

    const int px4 = threadIdx.x * 4;
    float acc[4][4];
#pragma unroll
    for (int c = 0; c < 4; c++) {
        float bv = bias[cog * 4 + c];
        acc[c][0] = bv; acc[c][1] = bv; acc[c][2] = bv; acc[c][3] = bv;
    }
#pragma unroll 4
    for (int ci = 0; ci < 32; ci++) {
        float4 x = *(const float4*)(in + (size_t)(b * 32 + ci) * 1024 + px4);
        float wv[4];
        ldw<4>(lw + ci * 4, wv);
#pragma unroll
        for (int c = 0; c < 4; c++) {
            acc[c][0] = fmaf(x.x, wv[c], acc[c][0]);
            acc[c][1] = fmaf(x.y, wv[c], acc[c][1]);
            acc[c][2] = fmaf(x.z, wv[c], acc[c][2]);
            acc[c][3] = fmaf(x.w, wv[c], acc[c][3]);
        }
    }
#pragma unroll
    for (int j = 0; j < 4; j++) {
        int pix = px4 + j;
        int row = pix >> 5, col = pix & 31;
        if (row >= 1 && row <= 30 && col >= 1 && col <= 30) {
            int pos = b * 900 + (row - 1) * 30 + (col - 1);
            float4 v;
            v.x = (acc[0][j] >= 0.f) ? acc[0][j] : LRELU * acc[0][j];
            v.y = (acc[1][j] >= 0.f) ? acc[1][j] : LRELU * acc[1][j];
            v.z = (acc[2][j] >= 0.f) ? acc[2][j] : LRELU * acc[2][j];
            v.w = (acc[3][j] >= 0.f) ? acc[3][j] : LRELU * acc[3][j];
            *(float4*)(latf + (size_t)pos * 64 + cog * 4) = v;
        }
    }
}

// ======================= d1 via code table (pad-2 output layout) ============
// out [64,32,30,(34)]: data cols 2..31, zero cols {1,32,33}.
__global__ __launch_bounds__(256)
void d1tab_k(const int* __restrict__ idxm, const float* __restrict__ U,
             const float* __restrict__ bias, float* __restrict__ out) {
    const int b = blockIdx.x, cog = blockIdx.y, rt = blockIdx.z;
    const int tx = threadIdx.x & 31, ty = threadIdx.x >> 5;
    const int r = rt * 8 + ty;
    if (r >= 30) return;
    if (tx >= 30) {
        if (tx == 31) {
#pragma unroll
            for (int c = 0; c < 16; c++) {
                float* base = out + (size_t)(b * 32 + cog * 16 + c) * 1020 + r * 34;
                base[1] = 0.f; base[32] = 0.f; base[33] = 0.f;
            }
        }
        return;
    }
    const int* im = idxm + b * 1024 + r * 32 + tx;
    float acc[16];
#pragma unroll
    for (int c = 0; c < 16; c++) acc[c] = bias[cog * 16 + c];
#pragma unroll
    for (int kh = 0; kh < 3; kh++) {
        int i0 = im[kh * 32 + 0];
        int i1 = im[kh * 32 + 1];
        int i2 = im[kh * 32 + 2];
        const float4* u0 = (const float4*)(U + ((size_t)i0 * 9 + kh * 3 + 0) * 32 + cog * 16);
        const float4* u1 = (const float4*)(U + ((size_t)i1 * 9 + kh * 3 + 1) * 32 + cog * 16);
        const float4* u2 = (const float4*)(U + ((size_t)i2 * 9 + kh * 3 + 2) * 32 + cog * 16);
#pragma unroll
        for (int q = 0; q < 4; q++) {
            float4 a = u0[q], bb = u1[q], cc = u2[q];
            acc[4*q+0] += (a.x + bb.x) + cc.x;
            acc[4*q+1] += (a.y + bb.y) + cc.y;
            acc[4*q+2] += (a.z + bb.z) + cc.z;
            acc[4*q+3] += (a.w + bb.w) + cc.w;
        }
    }
    float* ob = out + (size_t)(b * 32 + cog * 16) * 1020 + r * 34 + tx + 2;
#pragma unroll
    for (int c = 0; c < 16; c++) {
        float v = acc[c]; v = (v >= 0.f) ? v : LRELU * v;
        ob[(size_t)c * 1020] = v;
    }
}

// ======================= parity-fused convT k4 s2 (aligned float2 stores) ===
template<int CIN, int COUT, int CO_BLK, int HIN, int ISTR, int HOUT, int WOUT,
         int OPLANE, int OSTR, int OPADH, int NTX, int NT,
         int ZS_CH, int ZS_H, int ZS_STR, int ZC0, int ZC1, int ZC2,
         bool DO_TANH, bool DO_LOSS>
__global__ __launch_bounds__(256)
void convtf_k(const float* __restrict__ in, const float* __restrict__ wt,
              const float* __restrict__ bias, float* __restrict__ out,
              const float* __restrict__ loss, float* __restrict__ losstgt) {
    const int b = blockIdx.x, tid = threadIdx.x;
    const int NCOG = COUT / CO_BLK;
    int zz = blockIdx.z;
    if (zz >= NCOG * NT) {
        if (DO_LOSS) {
            if (b == 0 && tid == 0)
                losstgt[0] = 1.25f * loss[0] / (57600.f * 64.f);
            return;
        }
        int i = (zz - NCOG * NT) * 256 + tid;
        if (i >= ZS_CH * ZS_H * 3) return;
        int ch = i / (ZS_H * 3); int u = i - ch * ZS_H * 3;
        int r = u / 3, c3 = u - r * 3;
        int col = (c3 == 0) ? ZC0 : (c3 == 1) ? ZC1 : ZC2;
        out[((size_t)(b * ZS_CH + ch) * ZS_H + r) * ZS_STR + col] = 0.f;
        return;
    }
    const int cog = zz / NT, tile = zz - cog * NT;
    const int tlx = tile % NTX, tly = tile / NTX;

    __shared__ __align__(16) float lw[16 * CIN * CO_BLK];
    for (int i = tid; i < 16 * CIN * CO_BLK; i += 256) {
        int aq = i / (CIN * 4 * CO_BLK);
        int r1 = i - aq * (CIN * 4 * CO_BLK);
        int ci = r1 / (4 * CO_BLK);
        int u  = r1 - ci * (4 * CO_BLK);
        int pp = u / CO_BLK, c = u - pp * CO_BLK;
        int a = aq >> 1, q = aq & 1, py = pp >> 1, px = pp & 1;
        int tap = (py + 2 * a) * 4 + px + 2 * q;
        lw[i] = wt[((size_t)tap * CIN + ci) * COUT + cog * CO_BLK + c];
    }
    __syncthreads();

    const int SX = (WOUT + 1) >> 1, SY = (HOUT + 1) >> 1;
    const int sx0 = tlx * 32 + (tid & 15);
    const int sx1 = sx0 + 16;
    const int sy  = tly * 16 + (tid >> 4);
    const bool v0 = sx0 < SX, v1 = sx1 < SX;
    if (sy >= SY || !(v0 || v1)) return;

    const bool rvA = (sy < HIN);
    const bool rvB = (sy >= 1) && (sy <= HIN);

    float acc[2][4][CO_BLK];
#pragma unroll
    for (int s = 0; s < 2; s++)
#pragma unroll
        for (int o = 0; o < 4; o++)
#pragma unroll
            for (int c = 0; c < CO_BLK; c++)
                acc[s][o][c] = bias[cog * CO_BLK + c];

    const float* base = in + (size_t)(b * CIN) * HIN * ISTR;
#pragma unroll 2
    for (int ci = 0; ci < CIN; ci++) {
        const float* rowA = base + (size_t)ci * HIN * ISTR + (size_t)sy * ISTR;
        const float* rowB = rowA - ISTR;
        float rA0x = 0.f, rA0y = 0.f, rA1x = 0.f, rA1y = 0.f;
        float rB0x = 0.f, rB0y = 0.f, rB1x = 0.f, rB1y = 0.f;
        if (rvA) {
            if (v0) { rA0x = rowA[sx0]; rA0y = rowA[sx0 + 1]; }
            if (v1) { rA1x = rowA[sx1]; rA1y = rowA[sx1 + 1]; }
        }
        if (rvB) {
            if (v0) { rB0x = rowB[sx0]; rB0y = rowB[sx0 + 1]; }
            if (v1) { rB1x = rowB[sx1]; rB1y = rowB[sx1 + 1]; }
        }
#pragma unroll
        for (int a = 0; a < 2; a++) {
#pragma unroll
            for (int q = 0; q < 2; q++) {
                float iv0 = q ? (a ? rB0x : rA0x) : (a ? rB0y : rA0y);
                float iv1 = q ? (a ? rB1x : rA1x) : (a ? rB1y : rA1y);
                const float* wp = lw + (size_t)((a * 2 + q) * CIN + ci) * (4 * CO_BLK);
                float wv[4 * CO_BLK];
                ldw<4 * CO_BLK>(wp, wv);
#pragma unroll
                for (int o = 0; o < 4; o++)
#pragma unroll
                    for (int c = 0; c < CO_BLK; c++) {
                        acc[0][o][c] = fmaf(iv0, wv[o * CO_BLK + c], acc[0][o][c]);
                        acc[1][o][c] = fmaf(iv1, wv[o * CO_BLK + c], acc[1][o][c]);
                    }
            }
        }
    }
#pragma unroll
    for (int s = 0; s < 2; s++) {
        if (s ? !v1 : !v0) continue;
        const int sxx = s ? sx1 : sx0;
        const int ow = 2 * sxx;
        const bool full = (ow + 1) < WOUT;
#pragma unroll
        for (int py = 0; py < 2; py++) {
            int oh = 2 * sy + py;
            if (oh >= HOUT) continue;
            float* ob = out + (size_t)(b * COUT + cog * CO_BLK) * OPLANE
                            + (size_t)oh * OSTR + ow + OPADH;
#pragma unroll
            for (int c = 0; c < CO_BLK; c++) {
                float va = acc[s][py * 2 + 0][c];
                float vb = acc[s][py * 2 + 1][c];
                if (DO_TANH) { va = tanhf(va); vb = tanhf(vb); }
                else {
                    va = (va >= 0.f) ? va : LRELU * va;
                    vb = (vb >= 0.f) ? vb : LRELU * vb;
                }
                if ((OPADH & 1) == 0 && full) {
                    *(float2*)(ob + (size_t)c * OPLANE) = make_float2(va, vb);
                } else {
                    ob[(size_t)c * OPLANE] = va;
                    if (full) ob[(size_t)c * OPLANE + 1] = vb;
                }
            }
        }
    }
}

// ======================= VQ argmin (v9: best-of-series hybrid) ==============
// Series conclusion: r1's 2pos x 32dim LDS-broadcast structure is the
// measured best (69us, DS-bound: 9 DS instr/wave-k; 82% FMA density, one
// DPP hop). r8's 4pos x 16dim cut DS (5/k) but doubled the DPP/glue chain
// (56% density) -> 75us, chain-bound. v9 = r1 structure + its two defects
// fixed with verified-positive changes: NHWC latent loads (8 contiguous
// float4 vs 64 strided scalars) and grid.x=232 XCD alignment (r1's x=225
// scattered the 8 code-chunks across XCDs -> 63MB FETCH; 232 keeps them
// on one XCD, FETCH ~8MB, verified r0/r2-r8). This is the final variant:
// DS-bound floor ~69us vs 24us pure-FMA floor; scalar path blocked by
// compiler reload pathology (r2-r6); MFMA rejected (split-bf16 dot error
// ~5e-8 vs best/2nd-gap spacing ~1.2e-5 -> expected argmin flips).
template<int CTRL>
__device__ __forceinline__ float dpp_qp_add(float x) {
    int y = __builtin_amdgcn_update_dpp(0, __float_as_int(x), CTRL, 0xF, 0xF, true);
    return x + __int_as_float(y);
}

__global__ __launch_bounds__(256, 4)
void vq_argmin_k(const float* __restrict__ latf, const float* __restrict__ cb,
                 const float* __restrict__ hcbn,
                 unsigned long long* __restrict__ keys) {
    const int pb = blockIdx.x;
    if (pb >= 225) return;
    __shared__ float4 scb4[1024];   // 64 codes x 64 dims
    __shared__ float  shn[64];
    const int tid = threadIdx.x;
    const int dq  = tid & 1;        // dim half: dims [dq*32, dq*32+32)
    const int pg  = tid >> 1;       // 0..127
    const int kbase = blockIdx.y * 64;
    const int posbase = pb * 256;

    const float4* src = (const float4*)(cb + (size_t)kbase * 64);
#pragma unroll
    for (int i = 0; i < 4; i++) scb4[tid + 256 * i] = src[tid + 256 * i];
    if (tid < 64) shn[tid] = hcbn[kbase + tid];

    // 2 positions x 32 dims, NHWC-contiguous (8 float4 per position-half)
    float4 L[2][8];
    int pidx[2];
#pragma unroll
    for (int j = 0; j < 2; j++) {
        int pos = posbase + pg + 128 * j;
        pidx[j] = pos;
        const float4* lp = (const float4*)(latf + (size_t)pos * 64 + dq * 32);
#pragma unroll
        for (int u = 0; u < 8; u++) L[j][u] = lp[u];
    }
    __syncthreads();

    float best[2] = {3.4e38f, 3.4e38f};
    int   bi[2]   = {0, 0};
#pragma unroll 2
    for (int k = 0; k < 64; k++) {
        float4 c[8];
#pragma unroll
        for (int u = 0; u < 8; u++) c[u] = scb4[(k << 4) + (dq << 3) + u];
        float hn = shn[k];
#pragma unroll
        for (int j = 0; j < 2; j++) {
            float a0 = 0.f, a1 = 0.f;
#pragma unroll
            for (int u = 0; u < 8; u++) {
                a0 = fmaf(L[j][u].x, c[u].x, a0);
                a1 = fmaf(L[j][u].y, c[u].y, a1);
                a0 = fmaf(L[j][u].z, c[u].z, a0);
                a1 = fmaf(L[j][u].w, c[u].w, a1);
            }
            float dot = a0 + a1;
            float tot = dpp_qp_add<0xB1>(dot);  // quad_perm [1,0,3,2]: +lane^1
            float score = hn - tot;
            if (score < best[j]) { best[j] = score; bi[j] = kbase + k; }
        }
    }
    if (dq == 0) {
#pragma unroll
        for (int j = 0; j < 2; j++) {
            unsigned u = __float_as_uint(best[j]);
            u = ((int)u < 0) ? ~u : (u | 0x80000000u);
            unsigned long long key = ((unsigned long long)u << 32) | (unsigned)bi[j];
            atomicMin(&keys[pidx[j]], key);
        }
    }
}

// ======================= VQ finalize: idx-map + loss =======================
__global__ __launch_bounds__(256)
void vq_finalize_k(const float* __restrict__ latf, const float* __restrict__ cb,
                   const unsigned long long* __restrict__ keys,
                   int* __restrict__ idxm, float* __restrict__ loss_acc, int B) {
    int gid = blockIdx.x * 256 + threadIdx.x;
    const int N = B * 900;
    float myloss = 0.f;
    if (gid < N) {
        int b = gid / 900, p = gid - b * 900;
        int oh = p / 30, ow = p - oh * 30;
        int pp = 33 + oh * 32 + ow;
        int idx = (int)(unsigned)(keys[gid] & 0xFFFFFFFFull);
        idxm[b * 1024 + pp] = idx;
        const float4* crow = (const float4*)(cb + (size_t)idx * 64);
        const float4* lrow = (const float4*)(latf + (size_t)gid * 64);
#pragma unroll
        for (int i = 0; i < 16; i++) {
            float4 cv = crow[i];
            float4 lv = lrow[i];
            float d0 = cv.x - lv.x, d1 = cv.y - lv.y;
            float d2 = cv.z - lv.z, d3 = cv.w - lv.w;
            myloss = fmaf(d0, d0, myloss);
            myloss = fmaf(d1, d1, myloss);
            myloss = fmaf(d2, d2, myloss);
            myloss = fmaf(d3, d3, myloss);
        }
    }
    __shared__ float red[256];
    red[threadIdx.x] = myloss;
    __syncthreads();
    for (int s = 128; s > 0; s >>= 1) {
        if ((int)threadIdx.x < s) red[threadIdx.x] += red[threadIdx.x + s];
        __syncthreads();
    }
    if (threadIdx.x == 0) atomicAdd(loss_acc, red[0]);
}

static inline int nblk(long long total) { return (int)((total + 255) / 256); }

extern "C" void kernel_launch(void* const* d_in, const int* in_sizes, int n_in,
                              void* d_out, int out_size, void* d_ws, size_t ws_size,
                              hipStream_t stream) {
    const float* x   = (const float*)d_in[0];
    const float* ew1 = (const float*)d_in[1];  const float* eb1 = (const float*)d_in[2];
    const float* ew2 = (const float*)d_in[3];  const float* eb2 = (const float*)d_in[4];
    const float* ew3 = (const float*)d_in[5];  const float* eb3 = (const float*)d_in[6];
    const float* ew4 = (const float*)d_in[7];  const float* eb4 = (const float*)d_in[8];
    const float* ew5 = (const float*)d_in[9];  const float* eb5 = (const float*)d_in[10];
    const float* dw1 = (const float*)d_in[11]; const float* db1 = (const float*)d_in[12];
    const float* dw2 = (const float*)d_in[13]; const float* db2 = (const float*)d_in[14];
    const float* dw3 = (const float*)d_in[15]; const float* db3 = (const float*)d_in[16];
    const float* dw4 = (const float*)d_in[17]; const float* db4 = (const float*)d_in[18];
    const float* cb  = (const float*)d_in[19];
    float* out = (float*)d_out;

    const int B = in_sizes[0] / (256 * 256);   // 64
    const int N = B * 900;                     // 57600

    // ---- workspace map (liveness-audited; peak 53.2 MB) ----
    // [0, 34,873,344):  e1out -> e3out -> latf[57600][64] -> d1out -> d3out
    // [34,873,344, 52,420,608): e2out -> e4out -> d2out[64,16,63,68]
    //   (keys/hcbn/idxm tucked at its tail, all dead before d2 writes)
    // [52,420,608+): loss | wtb | U   (alive across decoder; outside both)
    char* ws = (char*)d_ws;
    float* A     = (float*)(ws);
    float* Bb    = (float*)(ws + 34873344);
    float* d2out = (float*)(ws + 34873344);
    float* d3out = (float*)(ws);
    unsigned long long* keys = (unsigned long long*)(ws + 51126272);
    float* hcbn  = (float*)(ws + 51587072);
    int*   idxm  = (int*)(ws + 51589120);
    float* loss  = (float*)(ws + 52420608);
    float* wtb   = (float*)(ws + 52420864);
    float* U     = (float*)(ws + 52622592);
    float* ew1t = wtb;          float* ew2t = wtb + 128;
    float* ew3t = wtb + 2176;   float* ew4t = wtb + 10368;
    float* ew5t = wtb + 19584;  float* dw1t = wtb + 21632;
    float* dw2t = wtb + 40064;  float* dw3t = wtb + 48256;
    float* dw4t = wtb + 50304;

    prep_k<<<nblk(50945 + N + 64 * 124), 256, 0, stream>>>(
        ew1, ew2, ew3, ew4, ew5, dw1, dw2, dw3, dw4, wtb,
        cb, hcbn, keys, loss, idxm, N);
    ubuild_k<<<nblk(513 * 288), 256, 0, stream>>>(dw1t, cb, U);

    // ---- encoder ----
    convs2_k<1, 8, 8, 256, 256, 127, 127, 127 * 128, 128, 0, 4, 8, 32, 0>
        <<<dim3(B, 1, 32), 256, 0, stream>>>(x, ew1t, eb1, A);
    convs2_k<8, 16, 4, 127, 128, 62, 62, 62 * 64, 64, 0, 2, 4, 8, 0>
        <<<dim3(B, 4, 8), 256, 0, stream>>>(A, ew2t, eb2, Bb);
    convs2_k<16, 32, 4, 62, 64, 30, 30, 1024, 32, 1, 1, 2, 2, 32>
        <<<dim3(B, 8, 18), 256, 0, stream>>>(Bb, ew3t, eb3, A);
    conv3_k<32, 32, 4, 1024, 32, 1, 1, false>
        <<<dim3(B, 8, 2), 256, 0, stream>>>(A, ew4t, eb4, Bb);
    // 1x1 conv writes NHWC latent latf = A  [57600 pos][64 dims]
    conv1nhwc_k<<<dim3(B, 16, 1), 256, 0, stream>>>(Bb, ew5t, eb5, A);

    // ---- VQ ----
    vq_argmin_k<<<dim3(232, 8), 256, 0, stream>>>(A, cb, hcbn, keys);
    vq_finalize_k<<<nblk(N), 256, 0, stream>>>(A, cb, keys, idxm, loss, B);

    // ---- decoder ----
    // d1 via code table -> A [64,32,30,(34)] pad-2 (latf dead)
    d1tab_k<<<dim3(B, 2, 4), 256, 0, stream>>>(idxm, U, db1, A);
    // d2: A(+1) -> d2out [64,16,63,(68)] pad-2, zero cols {1,65,66}
    convtf_k<32, 16, 4, 30, 34, 63, 63, 63 * 68, 68, 2, 1, 2,
             16, 63, 68, 1, 65, 66, false, false>
        <<<dim3(B, 1, 20), 256, 0, stream>>>(A + 1, dw2t, db2, d2out,
                                             nullptr, nullptr);
    // d3: d2out(+1) -> d3out=ws+0 [64,8,129,(132)] pad-2, zero cols {1,131}
    convtf_k<16, 8, 8, 63, 68, 129, 129, 129 * 132, 132, 2, 3, 15,
             8, 129, 132, 1, 1, 131, false, false>
        <<<dim3(B, 1, 28), 256, 0, stream>>>(d2out + 1, dw3t, db3, d3out,
                                             nullptr, nullptr);
    // d4: d3out(+1) -> out [64,1,260,260], tanh, + loss-final slice
    convtf_k<8, 1, 1, 129, 132, 260, 260, 67600, 260, 0, 5, 45,
             0, 1, 1, 0, 0, 0, true, true>
        <<<dim3(B, 1, 46), 256, 0, stream>>>(d3out + 1, dw4t, db4, out, loss,
                                             out + (out_size - 1));
}